// Round 8
// baseline (362.882 us; speedup 1.0000x reference)
//
#include <hip/hip_runtime.h>

#define HW 28
#define NPIX 784   // 28*28
#define NIMG 64
#define MAXD2 1459 // d2 <= 2*27^2 = 1458

// ---------------------------------------------------------------------------
// Kernel 1: grid distance-sort constants via LDS COUNTING SORT (O(N)/pixel).
// Tie order within a d2 bin is irrelevant for DTM (bin-constant d2 makes the
// water-fill contribution order-invariant).
// ---------------------------------------------------------------------------
__global__ void build_consts_kernel(unsigned short* __restrict__ sortIdx,
                                    unsigned short* __restrict__ d2s) {
    __shared__ int cnt[MAXD2];
    __shared__ int d2v[NPIX];
    __shared__ int wtot[4];
    int i = blockIdx.x;
    int tid = threadIdx.x;
    for (int b = tid; b < MAXD2; b += 256) cnt[b] = 0;
    __syncthreads();
    int ii = i / HW, ij = i % HW;
    for (int j = tid; j < NPIX; j += 256) {
        int di = ii - j / HW, dj = ij - j % HW;
        int d = di * di + dj * dj;
        d2v[j] = d;
        atomicAdd(&cnt[d], 1);
    }
    __syncthreads();
    int b0 = tid * 6;
    int lc[6];
    int s0 = 0;
    #pragma unroll
    for (int t = 0; t < 6; ++t) {
        int b = b0 + t;
        lc[t] = (b < MAXD2) ? cnt[b] : 0;
        s0 += lc[t];
    }
    int lane = tid & 63, wv = tid >> 6;
    int v = s0;
    for (int off = 1; off < 64; off <<= 1) {
        int t2 = __shfl_up(v, off, 64);
        if (lane >= off) v += t2;
    }
    if (lane == 63) wtot[wv] = v;
    __syncthreads();
    int wadd = 0;
    for (int w2 = 0; w2 < wv; ++w2) wadd += wtot[w2];
    int run = wadd + v - s0;
    __syncthreads();
    #pragma unroll
    for (int t = 0; t < 6; ++t) {
        int b = b0 + t;
        if (b < MAXD2) { cnt[b] = run; run += lc[t]; }
    }
    __syncthreads();
    for (int j = tid; j < NPIX; j += 256) {
        int d = d2v[j];
        int slot = atomicAdd(&cnt[d], 1);
        sortIdx[i * NPIX + slot] = (unsigned short)j;
        d2s[i * NPIX + slot] = (unsigned short)d;
    }
}

// ---------------------------------------------------------------------------
// Kernel 2: per-image sums (for the DTM mass bound).
// ---------------------------------------------------------------------------
__global__ void row_sum_kernel(const float* __restrict__ x, float* __restrict__ sums) {
    int m = blockIdx.x;
    float acc = 0.f;
    for (int j = threadIdx.x; j < NPIX; j += blockDim.x) acc += x[m * NPIX + j];
    for (int off = 32; off > 0; off >>= 1) acc += __shfl_down(acc, off, 64);
    __shared__ float red[4];
    int lane = threadIdx.x & 63, w = threadIdx.x >> 6;
    if (lane == 0) red[w] = acc;
    __syncthreads();
    if (threadIdx.x == 0) sums[m] = red[0] + red[1] + red[2] + red[3];
}

// ---------------------------------------------------------------------------
// Kernel 3: DTM. One wave per (m, i). Early exit once cum >= bound2.
// ---------------------------------------------------------------------------
__global__ void dtm_kernel(const float* __restrict__ x,
                           const unsigned short* __restrict__ sortIdx,
                           const unsigned short* __restrict__ d2s,
                           const float* __restrict__ sums,
                           float* __restrict__ F) {
    int wid = blockIdx.x * 4 + (threadIdx.x >> 6);
    int lane = threadIdx.x & 63;
    int m = wid / NPIX;
    int i = wid % NPIX;
    if (m >= NIMG) return;
    float s = sums[m];
    float bound1 = 0.05f * s, bound2 = 0.2f * s;
    const float* xr = x + m * NPIX;
    const unsigned short* si = sortIdx + (size_t)i * NPIX;
    const unsigned short* dr = d2s + (size_t)i * NPIX;
    float carry = 0.f, acc1 = 0.f, acc2 = 0.f;
    for (int c = 0; c < 7; ++c) {
        int j0 = c * 128 + lane * 2;
        float w0 = 0.f, w1 = 0.f, d0 = 0.f, d1 = 0.f;
        if (j0 < NPIX) {
            ushort2 sv = *(const ushort2*)(si + j0);
            ushort2 dv = *(const ushort2*)(dr + j0);
            w0 = xr[sv.x]; w1 = xr[sv.y];
            d0 = (float)dv.x; d1 = (float)dv.y;
        }
        float ps = w0 + w1;
        float v = ps;
        for (int off = 1; off < 64; off <<= 1) {
            float t = __shfl_up(v, off, 64);
            if (lane >= off) v += t;
        }
        float cum0 = carry + v - ps;
        float cum1 = cum0 + w0;
        acc1 += fminf(fmaxf(bound1 - cum0, 0.f), w0) * d0
              + fminf(fmaxf(bound1 - cum1, 0.f), w1) * d1;
        acc2 += fminf(fmaxf(bound2 - cum0, 0.f), w0) * d0
              + fminf(fmaxf(bound2 - cum1, 0.f), w1) * d1;
        carry += __shfl(v, 63, 64);
        if (carry >= bound2) break;   // wave-uniform: all later eff == 0
    }
    for (int off = 32; off > 0; off >>= 1) {
        acc1 += __shfl_down(acc1, off, 64);
        acc2 += __shfl_down(acc2, off, 64);
    }
    if (lane == 0) {
        F[0 * NIMG * NPIX + m * NPIX + i] = sqrtf(acc1 / bound1);
        F[1 * NIMG * NPIX + m * NPIX + i] = sqrtf(acc2 / bound2);
    }
}

// ---------------------------------------------------------------------------
// Kernel 4: stable ranks. task = feat*128 + dir*64 + m.
// ---------------------------------------------------------------------------
__global__ void rank_kernel(const float* __restrict__ F,
                            int* __restrict__ POS, int* __restrict__ ORD) {
    __shared__ float fv[NPIX];
    int task = blockIdx.x;
    int feat = task >> 7;
    int dir = (task >> 6) & 1;
    int m = task & 63;
    const float* fr = F + feat * NIMG * NPIX + m * NPIX;
    for (int j = threadIdx.x; j < NPIX; j += blockDim.x) fv[j] = fr[j];
    __syncthreads();
    int* pos = POS + task * NPIX;
    int* ord = ORD + task * NPIX;
    for (int i = threadIdx.x; i < NPIX; i += blockDim.x) {
        float fi = fv[i];
        int rank = 0;
        if (dir == 0) {
            for (int q = 0; q < NPIX; ++q) {
                float fq = fv[q];
                rank += (fq < fi) || (fq == fi && q < i);
            }
        } else {
            for (int q = 0; q < NPIX; ++q) {
                float fq = fv[q];
                rank += (fq > fi) || (fq == fi && q < i);
            }
        }
        pos[i] = rank;
        ord[rank] = i;
    }
}

// ---------------------------------------------------------------------------
// Kernel 5: fused union-find + landscape — EAGERLY-FLATTENED COMP KEYS.
// cell[p] = {pos, compkey}: compkey is ALWAYS the current packed root key
// (rootpos<<10|root); unadded vertices hold their self key.
// Phase A: ONE ds_read_b64 per edge slot — no find loop, no hops.
// Phase B: register-only (readlane + s_min + cndmask remap), as round 6.
// Batch end: if any merges, ordered (loserKey->winnerKey) entries from a
// small LDS list are applied to all 784 keys in parallel (relabel cost
// proportional to #pairs, which is tens per task).
// ---------------------------------------------------------------------------
template<int NN>   // NN = 4 (dir 0) or 8 (dir 1)
__device__ int uf_run(int2* cell, const int* ordA, int* pairsI, int2* mergeList) {
    const int lane = threadIdx.x;
    const int GB = 64 / NN;          // vertices per batch
    const int g = lane / NN;         // group id
    const int o = lane % NN;         // neighbor slot
    // packed dx/dy (+1, 2 bits each) for {-1,0},{1,0},{0,-1},{0,1},
    // {-1,-1},{-1,1},{1,-1},{1,1}
    const unsigned DXP = 41048u;
    const unsigned DYP = 34949u;
    const int dx = ((DXP >> (2 * o)) & 3) - 1;
    const int dy = ((DYP >> (2 * o)) & 3) - 1;
    const int INVALID = 0x100000 | lane;   // > any valid key (< 784<<10+1024)
    const unsigned long long lmask = (1ull << lane) - 1ull;
    int k = 0;

    int rj0 = 1 + g;
    int vv = ordA[(rj0 < NPIX) ? rj0 : 0];

    for (int rb = 1; rb < NPIX; rb += GB) {
        int rj = rb + g;
        bool act = (rj < NPIX);

        // ---- Phase A: single-read current-key fetch ----
        int key = INVALID;
        if (act) {
            int vi = vv / HW, vj2 = vv % HW;
            int ui = vi + dx, uj = vj2 + dy;
            if ((unsigned)ui < (unsigned)HW && (unsigned)uj < (unsigned)HW) {
                int x = ui * HW + uj;
                int2 e = cell[x];
                if (e.x < rj) key = e.y;     // added => key is CURRENT
            }
        }

        // prefetch next batch's vv (latency hidden behind Phase B)
        int rjN = rb + GB + g;
        int vvN = ordA[(rjN < NPIX) ? rjN : 0];

        int kb = k;                          // batch-start pair count

        // ---- Phase B: register-only resolution ----
        #pragma unroll
        for (int j = 0; j < GB; ++j) {
            if (rb + j >= NPIX) break;       // wave-uniform
            int kk[NN];
            #pragma unroll
            for (int t = 0; t < NN; ++t)
                kk[t] = __builtin_amdgcn_readlane(key, j * NN + t);
            int mn = kk[0];
            #pragma unroll
            for (int t = 1; t < NN; ++t) mn = min(mn, kk[t]);
            int vvj = __builtin_amdgcn_readlane(vv, j * NN);
            int sj = ((rb + j) << 10) | vvj; // v_j's self key
            int tj = min(mn, sj);            // valid keys < sj always
            int troot = tj;

            bool slow = false;
            #pragma unroll
            for (int t = 0; t < NN; ++t)
                slow = slow || (kk[t] < 0x100000 && kk[t] != mn);

            if (slow) {                      // >1 distinct component
                bool emit = (g == j) && (key < 0x100000) && (key != mn);
                #pragma unroll
                for (int t = 0; t < NN; ++t)
                    if (t < o && kk[t] == key) emit = false;   // dedupe
                unsigned long long em = __ballot(emit);
                if (emit) {
                    int slot = k + (int)__popcll(em & lmask);
                    pairsI[slot] = (key & 1023) | (vvj << 10);
                    mergeList[slot - kb] = make_int2(key, tj); // ordered entry
                }
                k += (int)__popcll(em);
                #pragma unroll
                for (int t = 0; t < NN; ++t)     // remap merged roots
                    key = (key == kk[t]) ? tj : key;
            }
            key = (key == sj) ? tj : key;        // in-batch self-root remap
            if (lane == j * NN) cell[vvj].y = troot;  // link v_j (current key)
        }

        // ---- batch-end eager relabel (rare; cost ~ #entries) ----
        int E = k - kb;
        if (E > 0) {
            for (int s = lane; s < NPIX; s += 64) {
                int c = cell[s].y;
                int c0 = c;
                for (int e = 0; e < E; ++e) {        // ordered application
                    int2 me = mergeList[e];          // broadcast read
                    c = (c == me.x) ? me.y : c;
                }
                if (c != c0) cell[s].y = c;
            }
        }
        vv = vvN;
    }
    return k;
}

__global__ void __launch_bounds__(64) uf_land_kernel(const int* __restrict__ POS,
                                                     const int* __restrict__ ORD,
                                                     const float* __restrict__ F,
                                                     float* __restrict__ LAM1,
                                                     float* __restrict__ LAM2) {
    __shared__ int2 cell[NPIX];     // {pos, current comp key}
    __shared__ int ordA[NPIX];
    __shared__ float fv[NPIX];      // this task's DTM values
    __shared__ int pairsI[NPIX];    // packed (root | v<<10)
    __shared__ float2 pairs[NPIX];  // (b, d) values
    __shared__ int2 mergeList[64];  // batch-local (loserKey -> winnerKey)
    int lane = threadIdx.x;
    int task = blockIdx.x;
    int feat = task >> 7;
    int dir = (task >> 6) & 1;
    int m = task & 63;
    const int* gpos = POS + task * NPIX;
    const int* gord = ORD + task * NPIX;
    const float* fr = F + feat * NIMG * NPIX + m * NPIX;
    for (int s = lane; s < NPIX; s += 64) {
        int p = gpos[s];
        cell[s] = make_int2(p, (p << 10) | s);   // self key
        ordA[s] = gord[s];
        fv[s] = fr[s];
    }
    __syncthreads();

    int k;
    if (dir == 0) k = uf_run<4>(cell, ordA, pairsI, mergeList);
    else          k = uf_run<8>(cell, ordA, pairsI, mergeList);
    __syncthreads();

    // convert packed pairs to (b, d) float values (dir 1 stores swapped)
    for (int s = lane; s < k; s += 64) {
        int p = pairsI[s];
        float fb = fv[p & 1023], fd = fv[p >> 10];
        pairs[s] = dir ? make_float2(fd, fb) : make_float2(fb, fd);
    }
    __syncthreads();

    // ---- fused landscape: top-3 tents over the k real pairs ----
    if (lane < 32) {
        int t = lane;
        float start = (feat == 0) ? 0.f : 1.f;
        float end   = (feat == 0) ? 7.f : 8.f;
        float tv = start + (end - start) * ((float)t / 31.f);
        float v0 = 0.f, v1 = 0.f, v2 = 0.f;
        for (int p = 0; p < k; ++p) {
            float2 bd = pairs[p];
            float tent = fmaxf(fminf(tv - bd.x, bd.y - tv), 0.f);
            if (tent > v0)      { v2 = v1; v1 = v0; v0 = tent; }
            else if (tent > v1) { v2 = v1; v1 = tent; }
            else if (tent > v2) { v2 = tent; }
        }
        if (feat == 0) {
            float* lam = LAM1 + m * 128 + dir * 64;
            lam[0 * 32 + t] = v0;
            lam[1 * 32 + t] = v1;
        } else {
            float* lam = LAM2 + m * 192 + dir * 96;
            lam[0 * 32 + t] = v0;
            lam[1 * 32 + t] = v1;
            lam[2 * 32 + t] = v2;
        }
    }
}

// ---------------------------------------------------------------------------
// Kernel 6: MLP head. One block (64 threads) per image.
// ---------------------------------------------------------------------------
__global__ void mlp_kernel(const float* __restrict__ LAM1, const float* __restrict__ LAM2,
                           const float* __restrict__ w1, const float* __restrict__ b1,
                           const float* __restrict__ w2, const float* __restrict__ b2,
                           const float* __restrict__ wf, const float* __restrict__ bf,
                           float* __restrict__ out) {
    __shared__ float xc[64];
    int m = blockIdx.x;
    int n = threadIdx.x;
    if (n < 32) {
        float acc = b1[n];
        const float* l = LAM1 + m * 128;
        for (int c = 0; c < 128; ++c) acc += w1[n * 128 + c] * l[c];
        xc[n] = fmaxf(acc, 0.f);
    } else {
        int n2 = n - 32;
        float acc = b2[n2];
        const float* l = LAM2 + m * 192;
        for (int c = 0; c < 192; ++c) acc += w2[n2 * 192 + c] * l[c];
        xc[n] = fmaxf(acc, 0.f);
    }
    __syncthreads();
    if (n < 10) {
        float acc = bf[n];
        for (int c = 0; c < 64; ++c) acc += wf[n * 64 + c] * xc[c];
        out[m * 10 + n] = acc;
    }
}

extern "C" void kernel_launch(void* const* d_in, const int* in_sizes, int n_in,
                              void* d_out, int out_size, void* d_ws, size_t ws_size,
                              hipStream_t stream) {
    const float* x  = (const float*)d_in[0];
    const float* w1 = (const float*)d_in[1];
    const float* b1 = (const float*)d_in[2];
    const float* w2 = (const float*)d_in[3];
    const float* b2 = (const float*)d_in[4];
    const float* wf = (const float*)d_in[5];
    const float* bf = (const float*)d_in[6];
    float* out = (float*)d_out;

    char* ws = (char*)d_ws;
    size_t off = 0;
    unsigned short* SORT = (unsigned short*)(ws + off); off += (size_t)NPIX * NPIX * 2;
    unsigned short* D2S  = (unsigned short*)(ws + off); off += (size_t)NPIX * NPIX * 2;
    float* SUMS = (float*)(ws + off); off += 256;
    float* F    = (float*)(ws + off); off += (size_t)2 * NIMG * NPIX * 4;
    int* POS    = (int*)(ws + off);   off += (size_t)256 * NPIX * 4;
    int* ORD    = (int*)(ws + off);   off += (size_t)256 * NPIX * 4;
    float* LAM1 = (float*)(ws + off); off += (size_t)NIMG * 128 * 4;
    float* LAM2 = (float*)(ws + off); off += (size_t)NIMG * 192 * 4;

    build_consts_kernel<<<NPIX, 256, 0, stream>>>(SORT, D2S);
    row_sum_kernel<<<NIMG, 256, 0, stream>>>(x, SUMS);
    dtm_kernel<<<(NIMG * NPIX) / 4, 256, 0, stream>>>(x, SORT, D2S, SUMS, F);
    rank_kernel<<<256, 256, 0, stream>>>(F, POS, ORD);
    uf_land_kernel<<<256, 64, 0, stream>>>(POS, ORD, F, LAM1, LAM2);
    mlp_kernel<<<NIMG, 64, 0, stream>>>(LAM1, LAM2, w1, b1, w2, b2, wf, bf, out);
}

// Round 10
// 303.559 us; speedup vs baseline: 1.1954x; 1.1954x over previous
//
#include <hip/hip_runtime.h>

#define HW 28
#define NPIX 784   // 28*28
#define NIMG 64
#define MAXD2 1459 // d2 <= 2*27^2 = 1458
#define MAXREC 5504  // 783 * 7 worst case

// packed dx/dy (+1, 2 bits each) for {-1,0},{1,0},{0,-1},{0,1},
// {-1,-1},{-1,1},{1,-1},{1,1}; first 4 = 4-connectivity
#define DXPK 41048u
#define DYPK 34949u

// ---------------------------------------------------------------------------
// Kernel 1: grid distance-sort constants via LDS counting sort.
// ---------------------------------------------------------------------------
__global__ void build_consts_kernel(unsigned short* __restrict__ sortIdx,
                                    unsigned short* __restrict__ d2s) {
    __shared__ int cnt[MAXD2];
    __shared__ int d2v[NPIX];
    __shared__ int wtot[4];
    int i = blockIdx.x;
    int tid = threadIdx.x;
    for (int b = tid; b < MAXD2; b += 256) cnt[b] = 0;
    __syncthreads();
    int ii = i / HW, ij = i % HW;
    for (int j = tid; j < NPIX; j += 256) {
        int di = ii - j / HW, dj = ij - j % HW;
        int d = di * di + dj * dj;
        d2v[j] = d;
        atomicAdd(&cnt[d], 1);
    }
    __syncthreads();
    int b0 = tid * 6;
    int lc[6];
    int s0 = 0;
    #pragma unroll
    for (int t = 0; t < 6; ++t) {
        int b = b0 + t;
        lc[t] = (b < MAXD2) ? cnt[b] : 0;
        s0 += lc[t];
    }
    int lane = tid & 63, wv = tid >> 6;
    int v = s0;
    for (int off = 1; off < 64; off <<= 1) {
        int t2 = __shfl_up(v, off, 64);
        if (lane >= off) v += t2;
    }
    if (lane == 63) wtot[wv] = v;
    __syncthreads();
    int wadd = 0;
    for (int w2 = 0; w2 < wv; ++w2) wadd += wtot[w2];
    int run = wadd + v - s0;
    __syncthreads();
    #pragma unroll
    for (int t = 0; t < 6; ++t) {
        int b = b0 + t;
        if (b < MAXD2) { cnt[b] = run; run += lc[t]; }
    }
    __syncthreads();
    for (int j = tid; j < NPIX; j += 256) {
        int d = d2v[j];
        int slot = atomicAdd(&cnt[d], 1);
        sortIdx[i * NPIX + slot] = (unsigned short)j;
        d2s[i * NPIX + slot] = (unsigned short)d;
    }
}

// ---------------------------------------------------------------------------
// Kernel 2: per-image sums.
// ---------------------------------------------------------------------------
__global__ void row_sum_kernel(const float* __restrict__ x, float* __restrict__ sums) {
    int m = blockIdx.x;
    float acc = 0.f;
    for (int j = threadIdx.x; j < NPIX; j += blockDim.x) acc += x[m * NPIX + j];
    for (int off = 32; off > 0; off >>= 1) acc += __shfl_down(acc, off, 64);
    __shared__ float red[4];
    int lane = threadIdx.x & 63, w = threadIdx.x >> 6;
    if (lane == 0) red[w] = acc;
    __syncthreads();
    if (threadIdx.x == 0) sums[m] = red[0] + red[1] + red[2] + red[3];
}

// ---------------------------------------------------------------------------
// Kernel 3: DTM. One wave per (m, i). Early exit once cum >= bound2.
// ---------------------------------------------------------------------------
__global__ void dtm_kernel(const float* __restrict__ x,
                           const unsigned short* __restrict__ sortIdx,
                           const unsigned short* __restrict__ d2s,
                           const float* __restrict__ sums,
                           float* __restrict__ F) {
    int wid = blockIdx.x * 4 + (threadIdx.x >> 6);
    int lane = threadIdx.x & 63;
    int m = wid / NPIX;
    int i = wid % NPIX;
    if (m >= NIMG) return;
    float s = sums[m];
    float bound1 = 0.05f * s, bound2 = 0.2f * s;
    const float* xr = x + m * NPIX;
    const unsigned short* si = sortIdx + (size_t)i * NPIX;
    const unsigned short* dr = d2s + (size_t)i * NPIX;
    float carry = 0.f, acc1 = 0.f, acc2 = 0.f;
    for (int c = 0; c < 7; ++c) {
        int j0 = c * 128 + lane * 2;
        float w0 = 0.f, w1 = 0.f, d0 = 0.f, d1 = 0.f;
        if (j0 < NPIX) {
            ushort2 sv = *(const ushort2*)(si + j0);
            ushort2 dv = *(const ushort2*)(dr + j0);
            w0 = xr[sv.x]; w1 = xr[sv.y];
            d0 = (float)dv.x; d1 = (float)dv.y;
        }
        float ps = w0 + w1;
        float v = ps;
        for (int off = 1; off < 64; off <<= 1) {
            float t = __shfl_up(v, off, 64);
            if (lane >= off) v += t;
        }
        float cum0 = carry + v - ps;
        float cum1 = cum0 + w0;
        acc1 += fminf(fmaxf(bound1 - cum0, 0.f), w0) * d0
              + fminf(fmaxf(bound1 - cum1, 0.f), w1) * d1;
        acc2 += fminf(fmaxf(bound2 - cum0, 0.f), w0) * d0
              + fminf(fmaxf(bound2 - cum1, 0.f), w1) * d1;
        carry += __shfl(v, 63, 64);
        if (carry >= bound2) break;   // wave-uniform: all later eff == 0
    }
    for (int off = 32; off > 0; off >>= 1) {
        acc1 += __shfl_down(acc1, off, 64);
        acc2 += __shfl_down(acc2, off, 64);
    }
    if (lane == 0) {
        F[0 * NIMG * NPIX + m * NPIX + i] = sqrtf(acc1 / bound1);
        F[1 * NIMG * NPIX + m * NPIX + i] = sqrtf(acc2 / bound2);
    }
}

// ---------------------------------------------------------------------------
// Kernel 4: stable ranks. task = feat*128 + dir*64 + m.
// ---------------------------------------------------------------------------
__global__ void rank_kernel(const float* __restrict__ F,
                            int* __restrict__ POS, int* __restrict__ ORD) {
    __shared__ float fv[NPIX];
    int task = blockIdx.x;
    int feat = task >> 7;
    int dir = (task >> 6) & 1;
    int m = task & 63;
    const float* fr = F + feat * NIMG * NPIX + m * NPIX;
    for (int j = threadIdx.x; j < NPIX; j += blockDim.x) fv[j] = fr[j];
    __syncthreads();
    int* pos = POS + task * NPIX;
    int* ord = ORD + task * NPIX;
    for (int i = threadIdx.x; i < NPIX; i += blockDim.x) {
        float fi = fv[i];
        int rank = 0;
        if (dir == 0) {
            for (int q = 0; q < NPIX; ++q) {
                float fq = fv[q];
                rank += (fq < fi) || (fq == fi && q < i);
            }
        } else {
            for (int q = 0; q < NPIX; ++q) {
                float fq = fv[q];
                rank += (fq > fi) || (fq == fi && q < i);
            }
        }
        pos[i] = rank;
        ord[rank] = i;
    }
}

// ---------------------------------------------------------------------------
// Kernel 5: fused UF + landscape via BASIN DECOMPOSITION. One wave per task.
//  P2: steepest-descent forest (parallel): parent = min-pos neighbor.
//  P3: pointer jumping (10 passes) -> basin root per vertex (static).
//  P4: candidate saddle records (v, bas[v], bas[u]) for distinct-basin added
//      neighbors, compacted in rank order (superset of true merges).
//  P5: serial UF over records in 64-record chunks: parallel pre-resolve vs
//      eagerly-flattened per-basin comp keys; register-only serial scan
//      (remap list = lane-distributed scalars via masked assign + readlane;
//      same-comp records skip in ~10 cyc); flatten comp[] after chunks that
//      merged. Winner = min packed key (elder rule).
// Pair SET == reference's nonzero-persistence set (order-invariant elder
// rule; (v,v) self pairs and (0,0) padding have tent == 0).
// ---------------------------------------------------------------------------
template<int NN>   // NN = 4 (dir 0) or 8 (dir 1)
__device__ int uf_basin_run(const int* posA, const int* ordA,
                            int* bas, int* comp, int* recs, int* pairsI) {
    const int lane = threadIdx.x;

    // ---- P2: forest init ----
    for (int s = lane; s < NPIX; s += 64) {
        int si = s / HW, sj = s % HW;
        int bestPos = posA[s], best = s;
        #pragma unroll
        for (int o = 0; o < NN; ++o) {
            int dx = ((DXPK >> (2 * o)) & 3) - 1;
            int dy = ((DYPK >> (2 * o)) & 3) - 1;
            int ui = si + dx, uj = sj + dy;
            if ((unsigned)ui < (unsigned)HW && (unsigned)uj < (unsigned)HW) {
                int u = ui * HW + uj;
                int pu = posA[u];
                if (pu < bestPos) { bestPos = pu; best = u; }
            }
        }
        bas[s] = best;
    }
    __syncthreads();

    // ---- P3: pointer jumping (2^10 = 1024 > max depth 783) ----
    for (int it = 0; it < 10; ++it) {
        for (int s = lane; s < NPIX; s += 64) {
            int b = bas[s];
            int bb = bas[b];
            if (bb != b) bas[s] = bb;
        }
        __syncthreads();
    }

    // ---- P4: candidate records, rank order ----
    int nrec = 0;
    for (int c = 0; c < 13; ++c) {
        int r = c * 64 + lane;
        int cnt = 0;
        int myr[NN - 1];
        int got[NN - 1];
        #pragma unroll
        for (int t = 0; t < NN - 1; ++t) { got[t] = -1; myr[t] = 0; }
        if (r > 0 && r < NPIX) {
            int v = ordA[r];
            int vi = v / HW, vj = v % HW;
            int pivot = bas[v];
            #pragma unroll
            for (int o = 0; o < NN; ++o) {
                int dx = ((DXPK >> (2 * o)) & 3) - 1;
                int dy = ((DYPK >> (2 * o)) & 3) - 1;
                int ui = vi + dx, uj = vj + dy;
                if ((unsigned)ui < (unsigned)HW && (unsigned)uj < (unsigned)HW) {
                    int u = ui * HW + uj;
                    if (posA[u] < r) {
                        int b = bas[u];
                        bool dup = (b == pivot);
                        #pragma unroll
                        for (int t = 0; t < NN - 1; ++t) dup = dup || (got[t] == b);
                        if (!dup) {
                            #pragma unroll
                            for (int t = 0; t < NN - 1; ++t)
                                if (t == cnt) { got[t] = b; myr[t] = (v << 20) | (pivot << 10) | b; }
                            cnt++;
                        }
                    }
                }
            }
        }
        // wave prefix-sum of cnt
        int p = cnt;
        for (int off = 1; off < 64; off <<= 1) {
            int t2 = __shfl_up(p, off, 64);
            if (lane >= off) p += t2;
        }
        int excl = p - cnt;
        int tot = __builtin_amdgcn_readlane(p, 63);
        #pragma unroll
        for (int t = 0; t < NN - 1; ++t)
            if (t < cnt) recs[nrec + excl + t] = myr[t];
        nrec += tot;
    }
    __syncthreads();

    // ---- P5: serial UF over records, 64-record chunks ----
    int k = 0;
    for (int base = 0; base < nrec; base += 64) {
        int idx = base + lane;
        int rec = (idx < nrec) ? recs[idx] : 0;
        int pa = (rec >> 10) & 1023, pbn = rec & 1023;
        int ka = 0, kb = 0;
        if (idx < nrec) { ka = comp[pa]; kb = comp[pbn]; }
        int n = nrec - base; if (n > 64) n = 64;
        int remSrc = 0, remDst = 0;   // lane-distributed remap entries
        int nrem = 0;
        for (int i = 0; i < n; ++i) {          // uniform serial scan
            int sA = __builtin_amdgcn_readlane(ka, i);
            int sB = __builtin_amdgcn_readlane(kb, i);
            for (int e = 0; e < nrem; ++e) {   // in-chunk remap (ordered)
                int rs = __builtin_amdgcn_readlane(remSrc, e);
                int rd = __builtin_amdgcn_readlane(remDst, e);
                sA = (sA == rs) ? rd : sA;
                sB = (sB == rs) ? rd : sB;
            }
            if (sA != sB) {                    // true merge (uniform branch)
                int w = min(sA, sB), l = max(sA, sB);
                int sv = __builtin_amdgcn_readlane(rec, i) >> 20;
                if (lane == 0) pairsI[k] = (l & 1023) | (sv << 10);
                k++;
                // "writelane": l, w are wave-uniform scalars
                if (lane == nrem) { remSrc = l; remDst = w; }
                nrem++;
                if (nrem == 63) {              // overflow guard (rare)
                    for (int s = lane; s < NPIX; s += 64) {
                        int cv = comp[s], c0 = cv;
                        for (int e = 0; e < nrem; ++e) {
                            int rs = __builtin_amdgcn_readlane(remSrc, e);
                            int rd = __builtin_amdgcn_readlane(remDst, e);
                            cv = (cv == rs) ? rd : cv;
                        }
                        if (cv != c0) comp[s] = cv;
                    }
                    if (idx < nrec) { ka = comp[pa]; kb = comp[pbn]; }
                    nrem = 0;
                }
            }
        }
        if (nrem > 0) {                        // flatten comp[] (rare)
            for (int s = lane; s < NPIX; s += 64) {
                int cv = comp[s], c0 = cv;
                for (int e = 0; e < nrem; ++e) {
                    int rs = __builtin_amdgcn_readlane(remSrc, e);
                    int rd = __builtin_amdgcn_readlane(remDst, e);
                    cv = (cv == rs) ? rd : cv;
                }
                if (cv != c0) comp[s] = cv;
            }
        }
        __syncthreads();
    }
    return k;
}

__global__ void __launch_bounds__(64) uf_land_kernel(const int* __restrict__ POS,
                                                     const int* __restrict__ ORD,
                                                     const float* __restrict__ F,
                                                     float* __restrict__ LAM1,
                                                     float* __restrict__ LAM2) {
    __shared__ int posA[NPIX], ordA[NPIX], bas[NPIX], comp[NPIX], pairsI[NPIX];
    __shared__ float fv[NPIX];
    __shared__ float2 pairs[NPIX];
    __shared__ int recs[MAXREC];
    int lane = threadIdx.x;
    int task = blockIdx.x;
    int feat = task >> 7;
    int dir = (task >> 6) & 1;
    int m = task & 63;
    const int* gpos = POS + task * NPIX;
    const int* gord = ORD + task * NPIX;
    const float* fr = F + feat * NIMG * NPIX + m * NPIX;
    for (int s = lane; s < NPIX; s += 64) {
        int p = gpos[s];
        posA[s] = p;
        comp[s] = (p << 10) | s;   // self key (valid at basin roots)
        ordA[s] = gord[s];
        fv[s] = fr[s];
    }
    __syncthreads();

    int k;
    if (dir == 0) k = uf_basin_run<4>(posA, ordA, bas, comp, recs, pairsI);
    else          k = uf_basin_run<8>(posA, ordA, bas, comp, recs, pairsI);
    __syncthreads();

    // convert packed pairs to (b, d) float values (dir 1 stores swapped)
    for (int s = lane; s < k; s += 64) {
        int p = pairsI[s];
        float fb = fv[p & 1023], fd = fv[p >> 10];
        pairs[s] = dir ? make_float2(fd, fb) : make_float2(fb, fd);
    }
    __syncthreads();

    // ---- fused landscape: top-3 tents over the k real pairs ----
    if (lane < 32) {
        int t = lane;
        float start = (feat == 0) ? 0.f : 1.f;
        float end   = (feat == 0) ? 7.f : 8.f;
        float tv = start + (end - start) * ((float)t / 31.f);
        float v0 = 0.f, v1 = 0.f, v2 = 0.f;
        for (int p = 0; p < k; ++p) {
            float2 bd = pairs[p];
            float tent = fmaxf(fminf(tv - bd.x, bd.y - tv), 0.f);
            if (tent > v0)      { v2 = v1; v1 = v0; v0 = tent; }
            else if (tent > v1) { v2 = v1; v1 = tent; }
            else if (tent > v2) { v2 = tent; }
        }
        if (feat == 0) {
            float* lam = LAM1 + m * 128 + dir * 64;
            lam[0 * 32 + t] = v0;
            lam[1 * 32 + t] = v1;
        } else {
            float* lam = LAM2 + m * 192 + dir * 96;
            lam[0 * 32 + t] = v0;
            lam[1 * 32 + t] = v1;
            lam[2 * 32 + t] = v2;
        }
    }
}

// ---------------------------------------------------------------------------
// Kernel 6: MLP head. One block (64 threads) per image.
// ---------------------------------------------------------------------------
__global__ void mlp_kernel(const float* __restrict__ LAM1, const float* __restrict__ LAM2,
                           const float* __restrict__ w1, const float* __restrict__ b1,
                           const float* __restrict__ w2, const float* __restrict__ b2,
                           const float* __restrict__ wf, const float* __restrict__ bf,
                           float* __restrict__ out) {
    __shared__ float xc[64];
    int m = blockIdx.x;
    int n = threadIdx.x;
    if (n < 32) {
        float acc = b1[n];
        const float* l = LAM1 + m * 128;
        for (int c = 0; c < 128; ++c) acc += w1[n * 128 + c] * l[c];
        xc[n] = fmaxf(acc, 0.f);
    } else {
        int n2 = n - 32;
        float acc = b2[n2];
        const float* l = LAM2 + m * 192;
        for (int c = 0; c < 192; ++c) acc += w2[n2 * 192 + c] * l[c];
        xc[n] = fmaxf(acc, 0.f);
    }
    __syncthreads();
    if (n < 10) {
        float acc = bf[n];
        for (int c = 0; c < 64; ++c) acc += wf[n * 64 + c] * xc[c];
        out[m * 10 + n] = acc;
    }
}

extern "C" void kernel_launch(void* const* d_in, const int* in_sizes, int n_in,
                              void* d_out, int out_size, void* d_ws, size_t ws_size,
                              hipStream_t stream) {
    const float* x  = (const float*)d_in[0];
    const float* w1 = (const float*)d_in[1];
    const float* b1 = (const float*)d_in[2];
    const float* w2 = (const float*)d_in[3];
    const float* b2 = (const float*)d_in[4];
    const float* wf = (const float*)d_in[5];
    const float* bf = (const float*)d_in[6];
    float* out = (float*)d_out;

    char* ws = (char*)d_ws;
    size_t off = 0;
    unsigned short* SORT = (unsigned short*)(ws + off); off += (size_t)NPIX * NPIX * 2;
    unsigned short* D2S  = (unsigned short*)(ws + off); off += (size_t)NPIX * NPIX * 2;
    float* SUMS = (float*)(ws + off); off += 256;
    float* F    = (float*)(ws + off); off += (size_t)2 * NIMG * NPIX * 4;
    int* POS    = (int*)(ws + off);   off += (size_t)256 * NPIX * 4;
    int* ORD    = (int*)(ws + off);   off += (size_t)256 * NPIX * 4;
    float* LAM1 = (float*)(ws + off); off += (size_t)NIMG * 128 * 4;
    float* LAM2 = (float*)(ws + off); off += (size_t)NIMG * 192 * 4;

    build_consts_kernel<<<NPIX, 256, 0, stream>>>(SORT, D2S);
    row_sum_kernel<<<NIMG, 256, 0, stream>>>(x, SUMS);
    dtm_kernel<<<(NIMG * NPIX) / 4, 256, 0, stream>>>(x, SORT, D2S, SUMS, F);
    rank_kernel<<<256, 256, 0, stream>>>(F, POS, ORD);
    uf_land_kernel<<<256, 64, 0, stream>>>(POS, ORD, F, LAM1, LAM2);
    mlp_kernel<<<NIMG, 64, 0, stream>>>(LAM1, LAM2, w1, b1, w2, b2, wf, bf, out);
}

// Round 11
// 244.805 us; speedup vs baseline: 1.4823x; 1.2400x over previous
//
#include <hip/hip_runtime.h>

#define HW 28
#define NPIX 784   // 28*28
#define NIMG 64
#define MAXD2 1459 // d2 <= 2*27^2 = 1458
#define MAXREC 5504  // 783 * 7 worst case

// packed dx/dy (+1, 2 bits each) for {-1,0},{1,0},{0,-1},{0,1},
// {-1,-1},{-1,1},{1,-1},{1,1}; first 4 = 4-connectivity
#define DXPK 41048u
#define DYPK 34949u

// ---------------------------------------------------------------------------
// Kernel 1: grid distance-sort constants via LDS counting sort.
// ---------------------------------------------------------------------------
__global__ void build_consts_kernel(unsigned short* __restrict__ sortIdx,
                                    unsigned short* __restrict__ d2s) {
    __shared__ int cnt[MAXD2];
    __shared__ int d2v[NPIX];
    __shared__ int wtot[4];
    int i = blockIdx.x;
    int tid = threadIdx.x;
    for (int b = tid; b < MAXD2; b += 256) cnt[b] = 0;
    __syncthreads();
    int ii = i / HW, ij = i % HW;
    for (int j = tid; j < NPIX; j += 256) {
        int di = ii - j / HW, dj = ij - j % HW;
        int d = di * di + dj * dj;
        d2v[j] = d;
        atomicAdd(&cnt[d], 1);
    }
    __syncthreads();
    int b0 = tid * 6;
    int lc[6];
    int s0 = 0;
    #pragma unroll
    for (int t = 0; t < 6; ++t) {
        int b = b0 + t;
        lc[t] = (b < MAXD2) ? cnt[b] : 0;
        s0 += lc[t];
    }
    int lane = tid & 63, wv = tid >> 6;
    int v = s0;
    for (int off = 1; off < 64; off <<= 1) {
        int t2 = __shfl_up(v, off, 64);
        if (lane >= off) v += t2;
    }
    if (lane == 63) wtot[wv] = v;
    __syncthreads();
    int wadd = 0;
    for (int w2 = 0; w2 < wv; ++w2) wadd += wtot[w2];
    int run = wadd + v - s0;
    __syncthreads();
    #pragma unroll
    for (int t = 0; t < 6; ++t) {
        int b = b0 + t;
        if (b < MAXD2) { cnt[b] = run; run += lc[t]; }
    }
    __syncthreads();
    for (int j = tid; j < NPIX; j += 256) {
        int d = d2v[j];
        int slot = atomicAdd(&cnt[d], 1);
        sortIdx[i * NPIX + slot] = (unsigned short)j;
        d2s[i * NPIX + slot] = (unsigned short)d;
    }
}

// ---------------------------------------------------------------------------
// Kernel 2: per-image sums.
// ---------------------------------------------------------------------------
__global__ void row_sum_kernel(const float* __restrict__ x, float* __restrict__ sums) {
    int m = blockIdx.x;
    float acc = 0.f;
    for (int j = threadIdx.x; j < NPIX; j += blockDim.x) acc += x[m * NPIX + j];
    for (int off = 32; off > 0; off >>= 1) acc += __shfl_down(acc, off, 64);
    __shared__ float red[4];
    int lane = threadIdx.x & 63, w = threadIdx.x >> 6;
    if (lane == 0) red[w] = acc;
    __syncthreads();
    if (threadIdx.x == 0) sums[m] = red[0] + red[1] + red[2] + red[3];
}

// ---------------------------------------------------------------------------
// Kernel 3: DTM. One wave per (m, i). Early exit once cum >= bound2.
// ---------------------------------------------------------------------------
__global__ void dtm_kernel(const float* __restrict__ x,
                           const unsigned short* __restrict__ sortIdx,
                           const unsigned short* __restrict__ d2s,
                           const float* __restrict__ sums,
                           float* __restrict__ F) {
    int wid = blockIdx.x * 4 + (threadIdx.x >> 6);
    int lane = threadIdx.x & 63;
    int m = wid / NPIX;
    int i = wid % NPIX;
    if (m >= NIMG) return;
    float s = sums[m];
    float bound1 = 0.05f * s, bound2 = 0.2f * s;
    const float* xr = x + m * NPIX;
    const unsigned short* si = sortIdx + (size_t)i * NPIX;
    const unsigned short* dr = d2s + (size_t)i * NPIX;
    float carry = 0.f, acc1 = 0.f, acc2 = 0.f;
    for (int c = 0; c < 7; ++c) {
        int j0 = c * 128 + lane * 2;
        float w0 = 0.f, w1 = 0.f, d0 = 0.f, d1 = 0.f;
        if (j0 < NPIX) {
            ushort2 sv = *(const ushort2*)(si + j0);
            ushort2 dv = *(const ushort2*)(dr + j0);
            w0 = xr[sv.x]; w1 = xr[sv.y];
            d0 = (float)dv.x; d1 = (float)dv.y;
        }
        float ps = w0 + w1;
        float v = ps;
        for (int off = 1; off < 64; off <<= 1) {
            float t = __shfl_up(v, off, 64);
            if (lane >= off) v += t;
        }
        float cum0 = carry + v - ps;
        float cum1 = cum0 + w0;
        acc1 += fminf(fmaxf(bound1 - cum0, 0.f), w0) * d0
              + fminf(fmaxf(bound1 - cum1, 0.f), w1) * d1;
        acc2 += fminf(fmaxf(bound2 - cum0, 0.f), w0) * d0
              + fminf(fmaxf(bound2 - cum1, 0.f), w1) * d1;
        carry += __shfl(v, 63, 64);
        if (carry >= bound2) break;   // wave-uniform: all later eff == 0
    }
    for (int off = 32; off > 0; off >>= 1) {
        acc1 += __shfl_down(acc1, off, 64);
        acc2 += __shfl_down(acc2, off, 64);
    }
    if (lane == 0) {
        F[0 * NIMG * NPIX + m * NPIX + i] = sqrtf(acc1 / bound1);
        F[1 * NIMG * NPIX + m * NPIX + i] = sqrtf(acc2 / bound2);
    }
}

// ---------------------------------------------------------------------------
// Kernel 4: stable ranks. task = feat*128 + dir*64 + m.
// ---------------------------------------------------------------------------
__global__ void rank_kernel(const float* __restrict__ F,
                            int* __restrict__ POS, int* __restrict__ ORD) {
    __shared__ float fv[NPIX];
    int task = blockIdx.x;
    int feat = task >> 7;
    int dir = (task >> 6) & 1;
    int m = task & 63;
    const float* fr = F + feat * NIMG * NPIX + m * NPIX;
    for (int j = threadIdx.x; j < NPIX; j += blockDim.x) fv[j] = fr[j];
    __syncthreads();
    int* pos = POS + task * NPIX;
    int* ord = ORD + task * NPIX;
    for (int i = threadIdx.x; i < NPIX; i += blockDim.x) {
        float fi = fv[i];
        int rank = 0;
        if (dir == 0) {
            for (int q = 0; q < NPIX; ++q) {
                float fq = fv[q];
                rank += (fq < fi) || (fq == fi && q < i);
            }
        } else {
            for (int q = 0; q < NPIX; ++q) {
                float fq = fv[q];
                rank += (fq > fi) || (fq == fi && q < i);
            }
        }
        pos[i] = rank;
        ord[rank] = i;
    }
}

// ---------------------------------------------------------------------------
// Kernel 5: fused UF + landscape via BASIN DECOMPOSITION. One wave per task.
//  P2: steepest-descent forest; P3: pointer jumping -> basin labels;
//  P4: candidate saddle records in rank order (superset of merges);
//  P5: BALLOT-DRIVEN resolution: per 64-record chunk, ka/kb registers are
//      kept current in parallel (2 cndmasks per merge across all lanes);
//      ballot(ka!=kb) + ffs picks the next merge in rank order; cost per
//      NON-merging record ~ 0. comp[] flattened (ordered remap entries)
//      only after chunks that merged. Winner = min packed key (elder rule).
// Pair SET == reference's nonzero-persistence set (order-invariant elder
// rule; (v,v) self pairs and (0,0) padding have tent == 0).
// ---------------------------------------------------------------------------
template<int NN>   // NN = 4 (dir 0) or 8 (dir 1)
__device__ int uf_basin_run(const int* posA, const int* ordA,
                            int* bas, int* comp, int* recs, int* pairsI) {
    const int lane = threadIdx.x;

    // ---- P2: forest init ----
    for (int s = lane; s < NPIX; s += 64) {
        int si = s / HW, sj = s % HW;
        int bestPos = posA[s], best = s;
        #pragma unroll
        for (int o = 0; o < NN; ++o) {
            int dx = ((DXPK >> (2 * o)) & 3) - 1;
            int dy = ((DYPK >> (2 * o)) & 3) - 1;
            int ui = si + dx, uj = sj + dy;
            if ((unsigned)ui < (unsigned)HW && (unsigned)uj < (unsigned)HW) {
                int u = ui * HW + uj;
                int pu = posA[u];
                if (pu < bestPos) { bestPos = pu; best = u; }
            }
        }
        bas[s] = best;
    }
    __syncthreads();

    // ---- P3: pointer jumping (2^10 = 1024 > max depth 783) ----
    for (int it = 0; it < 10; ++it) {
        for (int s = lane; s < NPIX; s += 64) {
            int b = bas[s];
            int bb = bas[b];
            if (bb != b) bas[s] = bb;
        }
        __syncthreads();
    }

    // ---- P4: candidate records, rank order ----
    int nrec = 0;
    for (int c = 0; c < 13; ++c) {
        int r = c * 64 + lane;
        int cnt = 0;
        int myr[NN - 1];
        int got[NN - 1];
        #pragma unroll
        for (int t = 0; t < NN - 1; ++t) { got[t] = -1; myr[t] = 0; }
        if (r > 0 && r < NPIX) {
            int v = ordA[r];
            int vi = v / HW, vj = v % HW;
            int pivot = bas[v];
            #pragma unroll
            for (int o = 0; o < NN; ++o) {
                int dx = ((DXPK >> (2 * o)) & 3) - 1;
                int dy = ((DYPK >> (2 * o)) & 3) - 1;
                int ui = vi + dx, uj = vj + dy;
                if ((unsigned)ui < (unsigned)HW && (unsigned)uj < (unsigned)HW) {
                    int u = ui * HW + uj;
                    if (posA[u] < r) {
                        int b = bas[u];
                        bool dup = (b == pivot);
                        #pragma unroll
                        for (int t = 0; t < NN - 1; ++t) dup = dup || (got[t] == b);
                        if (!dup) {
                            #pragma unroll
                            for (int t = 0; t < NN - 1; ++t)
                                if (t == cnt) { got[t] = b; myr[t] = (v << 20) | (pivot << 10) | b; }
                            cnt++;
                        }
                    }
                }
            }
        }
        // wave prefix-sum of cnt
        int p = cnt;
        for (int off = 1; off < 64; off <<= 1) {
            int t2 = __shfl_up(p, off, 64);
            if (lane >= off) p += t2;
        }
        int excl = p - cnt;
        int tot = __builtin_amdgcn_readlane(p, 63);
        #pragma unroll
        for (int t = 0; t < NN - 1; ++t)
            if (t < cnt) recs[nrec + excl + t] = myr[t];
        nrec += tot;
    }
    __syncthreads();

    // ---- P5: ballot-driven UF over records, 64-record chunks ----
    int k = 0;
    for (int base = 0; base < nrec; base += 64) {
        int idx = base + lane;
        int rec = (idx < nrec) ? recs[idx] : 0;
        int pa = (rec >> 10) & 1023, pbn = rec & 1023;
        int ka = 0, kb = 0;
        if (idx < nrec) { ka = comp[pa]; kb = comp[pbn]; }
        int remSrc = 0, remDst = 0;   // lane-distributed remap entries
        int nrem = 0;
        for (;;) {
            unsigned long long d = __ballot(ka != kb);
            if (d == 0ull) break;
            int i = (int)__ffsll((long long)d) - 1;   // lowest lane = lowest rank
            int sA = __builtin_amdgcn_readlane(ka, i);
            int sB = __builtin_amdgcn_readlane(kb, i);
            int w = min(sA, sB), l = max(sA, sB);     // uniform scalars
            int sv = __builtin_amdgcn_readlane(rec, i) >> 20;
            if (lane == 0) pairsI[k] = (l & 1023) | (sv << 10);
            k++;
            // keep ALL lanes' keys current (parallel, 2 cndmasks)
            ka = (ka == l) ? w : ka;
            kb = (kb == l) ? w : kb;
            // record remap entry for the comp[] flatten ("writelane")
            if (lane == nrem) { remSrc = l; remDst = w; }
            nrem++;
            if (nrem == 63) {              // overflow guard (rare)
                for (int s = lane; s < NPIX; s += 64) {
                    int cv = comp[s], c0 = cv;
                    for (int e = 0; e < nrem; ++e) {
                        int rs = __builtin_amdgcn_readlane(remSrc, e);
                        int rd = __builtin_amdgcn_readlane(remDst, e);
                        cv = (cv == rs) ? rd : cv;
                    }
                    if (cv != c0) comp[s] = cv;
                }
                if (idx < nrec) { ka = comp[pa]; kb = comp[pbn]; }
                nrem = 0;
            }
        }
        if (nrem > 0) {                    // flatten comp[] (ordered entries)
            for (int s = lane; s < NPIX; s += 64) {
                int cv = comp[s], c0 = cv;
                for (int e = 0; e < nrem; ++e) {
                    int rs = __builtin_amdgcn_readlane(remSrc, e);
                    int rd = __builtin_amdgcn_readlane(remDst, e);
                    cv = (cv == rs) ? rd : cv;
                }
                if (cv != c0) comp[s] = cv;
            }
        }
        __syncthreads();
    }
    return k;
}

__global__ void __launch_bounds__(64) uf_land_kernel(const int* __restrict__ POS,
                                                     const int* __restrict__ ORD,
                                                     const float* __restrict__ F,
                                                     float* __restrict__ LAM1,
                                                     float* __restrict__ LAM2) {
    __shared__ int posA[NPIX], ordA[NPIX], bas[NPIX], comp[NPIX], pairsI[NPIX];
    __shared__ float fv[NPIX];
    __shared__ float2 pairs[NPIX];
    __shared__ int recs[MAXREC];
    int lane = threadIdx.x;
    int task = blockIdx.x;
    int feat = task >> 7;
    int dir = (task >> 6) & 1;
    int m = task & 63;
    const int* gpos = POS + task * NPIX;
    const int* gord = ORD + task * NPIX;
    const float* fr = F + feat * NIMG * NPIX + m * NPIX;
    for (int s = lane; s < NPIX; s += 64) {
        int p = gpos[s];
        posA[s] = p;
        comp[s] = (p << 10) | s;   // self key (valid at basin roots)
        ordA[s] = gord[s];
        fv[s] = fr[s];
    }
    __syncthreads();

    int k;
    if (dir == 0) k = uf_basin_run<4>(posA, ordA, bas, comp, recs, pairsI);
    else          k = uf_basin_run<8>(posA, ordA, bas, comp, recs, pairsI);
    __syncthreads();

    // convert packed pairs to (b, d) float values (dir 1 stores swapped)
    for (int s = lane; s < k; s += 64) {
        int p = pairsI[s];
        float fb = fv[p & 1023], fd = fv[p >> 10];
        pairs[s] = dir ? make_float2(fd, fb) : make_float2(fb, fd);
    }
    __syncthreads();

    // ---- fused landscape: top-3 tents over the k real pairs ----
    if (lane < 32) {
        int t = lane;
        float start = (feat == 0) ? 0.f : 1.f;
        float end   = (feat == 0) ? 7.f : 8.f;
        float tv = start + (end - start) * ((float)t / 31.f);
        float v0 = 0.f, v1 = 0.f, v2 = 0.f;
        for (int p = 0; p < k; ++p) {
            float2 bd = pairs[p];
            float tent = fmaxf(fminf(tv - bd.x, bd.y - tv), 0.f);
            if (tent > v0)      { v2 = v1; v1 = v0; v0 = tent; }
            else if (tent > v1) { v2 = v1; v1 = tent; }
            else if (tent > v2) { v2 = tent; }
        }
        if (feat == 0) {
            float* lam = LAM1 + m * 128 + dir * 64;
            lam[0 * 32 + t] = v0;
            lam[1 * 32 + t] = v1;
        } else {
            float* lam = LAM2 + m * 192 + dir * 96;
            lam[0 * 32 + t] = v0;
            lam[1 * 32 + t] = v1;
            lam[2 * 32 + t] = v2;
        }
    }
}

// ---------------------------------------------------------------------------
// Kernel 6: MLP head. One block (64 threads) per image.
// ---------------------------------------------------------------------------
__global__ void mlp_kernel(const float* __restrict__ LAM1, const float* __restrict__ LAM2,
                           const float* __restrict__ w1, const float* __restrict__ b1,
                           const float* __restrict__ w2, const float* __restrict__ b2,
                           const float* __restrict__ wf, const float* __restrict__ bf,
                           float* __restrict__ out) {
    __shared__ float xc[64];
    int m = blockIdx.x;
    int n = threadIdx.x;
    if (n < 32) {
        float acc = b1[n];
        const float* l = LAM1 + m * 128;
        for (int c = 0; c < 128; ++c) acc += w1[n * 128 + c] * l[c];
        xc[n] = fmaxf(acc, 0.f);
    } else {
        int n2 = n - 32;
        float acc = b2[n2];
        const float* l = LAM2 + m * 192;
        for (int c = 0; c < 192; ++c) acc += w2[n2 * 192 + c] * l[c];
        xc[n] = fmaxf(acc, 0.f);
    }
    __syncthreads();
    if (n < 10) {
        float acc = bf[n];
        for (int c = 0; c < 64; ++c) acc += wf[n * 64 + c] * xc[c];
        out[m * 10 + n] = acc;
    }
}

extern "C" void kernel_launch(void* const* d_in, const int* in_sizes, int n_in,
                              void* d_out, int out_size, void* d_ws, size_t ws_size,
                              hipStream_t stream) {
    const float* x  = (const float*)d_in[0];
    const float* w1 = (const float*)d_in[1];
    const float* b1 = (const float*)d_in[2];
    const float* w2 = (const float*)d_in[3];
    const float* b2 = (const float*)d_in[4];
    const float* wf = (const float*)d_in[5];
    const float* bf = (const float*)d_in[6];
    float* out = (float*)d_out;

    char* ws = (char*)d_ws;
    size_t off = 0;
    unsigned short* SORT = (unsigned short*)(ws + off); off += (size_t)NPIX * NPIX * 2;
    unsigned short* D2S  = (unsigned short*)(ws + off); off += (size_t)NPIX * NPIX * 2;
    float* SUMS = (float*)(ws + off); off += 256;
    float* F    = (float*)(ws + off); off += (size_t)2 * NIMG * NPIX * 4;
    int* POS    = (int*)(ws + off);   off += (size_t)256 * NPIX * 4;
    int* ORD    = (int*)(ws + off);   off += (size_t)256 * NPIX * 4;
    float* LAM1 = (float*)(ws + off); off += (size_t)NIMG * 128 * 4;
    float* LAM2 = (float*)(ws + off); off += (size_t)NIMG * 192 * 4;

    build_consts_kernel<<<NPIX, 256, 0, stream>>>(SORT, D2S);
    row_sum_kernel<<<NIMG, 256, 0, stream>>>(x, SUMS);
    dtm_kernel<<<(NIMG * NPIX) / 4, 256, 0, stream>>>(x, SORT, D2S, SUMS, F);
    rank_kernel<<<256, 256, 0, stream>>>(F, POS, ORD);
    uf_land_kernel<<<256, 64, 0, stream>>>(POS, ORD, F, LAM1, LAM2);
    mlp_kernel<<<NIMG, 64, 0, stream>>>(LAM1, LAM2, w1, b1, w2, b2, wf, bf, out);
}

// Round 12
// 201.249 us; speedup vs baseline: 1.8031x; 1.2164x over previous
//
#include <hip/hip_runtime.h>

#define HW 28
#define NPIX 784   // 28*28
#define NIMG 64
#define MAXD2 1459 // d2 <= 2*27^2 = 1458
#define MAXREC 5504  // 783 * 7 worst case

// packed dx/dy (+1, 2 bits each) for {-1,0},{1,0},{0,-1},{0,1},
// {-1,-1},{-1,1},{1,-1},{1,1}; first 4 = 4-connectivity
#define DXPK 41048u
#define DYPK 34949u

// ---------------------------------------------------------------------------
// Kernel 1: grid distance-sort constants via LDS counting sort.
// ---------------------------------------------------------------------------
__global__ void build_consts_kernel(unsigned short* __restrict__ sortIdx,
                                    unsigned short* __restrict__ d2s) {
    __shared__ int cnt[MAXD2];
    __shared__ int d2v[NPIX];
    __shared__ int wtot[4];
    int i = blockIdx.x;
    int tid = threadIdx.x;
    for (int b = tid; b < MAXD2; b += 256) cnt[b] = 0;
    __syncthreads();
    int ii = i / HW, ij = i % HW;
    for (int j = tid; j < NPIX; j += 256) {
        int di = ii - j / HW, dj = ij - j % HW;
        int d = di * di + dj * dj;
        d2v[j] = d;
        atomicAdd(&cnt[d], 1);
    }
    __syncthreads();
    int b0 = tid * 6;
    int lc[6];
    int s0 = 0;
    #pragma unroll
    for (int t = 0; t < 6; ++t) {
        int b = b0 + t;
        lc[t] = (b < MAXD2) ? cnt[b] : 0;
        s0 += lc[t];
    }
    int lane = tid & 63, wv = tid >> 6;
    int v = s0;
    for (int off = 1; off < 64; off <<= 1) {
        int t2 = __shfl_up(v, off, 64);
        if (lane >= off) v += t2;
    }
    if (lane == 63) wtot[wv] = v;
    __syncthreads();
    int wadd = 0;
    for (int w2 = 0; w2 < wv; ++w2) wadd += wtot[w2];
    int run = wadd + v - s0;
    __syncthreads();
    #pragma unroll
    for (int t = 0; t < 6; ++t) {
        int b = b0 + t;
        if (b < MAXD2) { cnt[b] = run; run += lc[t]; }
    }
    __syncthreads();
    for (int j = tid; j < NPIX; j += 256) {
        int d = d2v[j];
        int slot = atomicAdd(&cnt[d], 1);
        sortIdx[i * NPIX + slot] = (unsigned short)j;
        d2s[i * NPIX + slot] = (unsigned short)d;
    }
}

// ---------------------------------------------------------------------------
// Kernel 2: per-image sums.
// ---------------------------------------------------------------------------
__global__ void row_sum_kernel(const float* __restrict__ x, float* __restrict__ sums) {
    int m = blockIdx.x;
    float acc = 0.f;
    for (int j = threadIdx.x; j < NPIX; j += blockDim.x) acc += x[m * NPIX + j];
    for (int off = 32; off > 0; off >>= 1) acc += __shfl_down(acc, off, 64);
    __shared__ float red[4];
    int lane = threadIdx.x & 63, w = threadIdx.x >> 6;
    if (lane == 0) red[w] = acc;
    __syncthreads();
    if (threadIdx.x == 0) sums[m] = red[0] + red[1] + red[2] + red[3];
}

// ---------------------------------------------------------------------------
// Kernel 3: DTM. One wave per (m, i). Early exit once cum >= bound2.
// ---------------------------------------------------------------------------
__global__ void dtm_kernel(const float* __restrict__ x,
                           const unsigned short* __restrict__ sortIdx,
                           const unsigned short* __restrict__ d2s,
                           const float* __restrict__ sums,
                           float* __restrict__ F) {
    int wid = blockIdx.x * 4 + (threadIdx.x >> 6);
    int lane = threadIdx.x & 63;
    int m = wid / NPIX;
    int i = wid % NPIX;
    if (m >= NIMG) return;
    float s = sums[m];
    float bound1 = 0.05f * s, bound2 = 0.2f * s;
    const float* xr = x + m * NPIX;
    const unsigned short* si = sortIdx + (size_t)i * NPIX;
    const unsigned short* dr = d2s + (size_t)i * NPIX;
    float carry = 0.f, acc1 = 0.f, acc2 = 0.f;
    for (int c = 0; c < 7; ++c) {
        int j0 = c * 128 + lane * 2;
        float w0 = 0.f, w1 = 0.f, d0 = 0.f, d1 = 0.f;
        if (j0 < NPIX) {
            ushort2 sv = *(const ushort2*)(si + j0);
            ushort2 dv = *(const ushort2*)(dr + j0);
            w0 = xr[sv.x]; w1 = xr[sv.y];
            d0 = (float)dv.x; d1 = (float)dv.y;
        }
        float ps = w0 + w1;
        float v = ps;
        for (int off = 1; off < 64; off <<= 1) {
            float t = __shfl_up(v, off, 64);
            if (lane >= off) v += t;
        }
        float cum0 = carry + v - ps;
        float cum1 = cum0 + w0;
        acc1 += fminf(fmaxf(bound1 - cum0, 0.f), w0) * d0
              + fminf(fmaxf(bound1 - cum1, 0.f), w1) * d1;
        acc2 += fminf(fmaxf(bound2 - cum0, 0.f), w0) * d0
              + fminf(fmaxf(bound2 - cum1, 0.f), w1) * d1;
        carry += __shfl(v, 63, 64);
        if (carry >= bound2) break;   // wave-uniform: all later eff == 0
    }
    for (int off = 32; off > 0; off >>= 1) {
        acc1 += __shfl_down(acc1, off, 64);
        acc2 += __shfl_down(acc2, off, 64);
    }
    if (lane == 0) {
        F[0 * NIMG * NPIX + m * NPIX + i] = sqrtf(acc1 / bound1);
        F[1 * NIMG * NPIX + m * NPIX + i] = sqrtf(acc2 / bound2);
    }
}

// ---------------------------------------------------------------------------
// Kernel 4: stable ranks — register-blocked, b128 LDS reads, u64 packed keys.
// DTM values >= 0 so IEEE bits are order-isomorphic; LDS holds
// dir-adjusted keys (dir ? ~bits : bits), making both directions the same
// ascending compare. rank(i) = #{q: (kq<<10|q) < (ki<<10|i)} — exact stable
// tie-break by index. 4 rows/thread in registers, uint4 per LDS read.
// ---------------------------------------------------------------------------
__global__ void rank_kernel(const float* __restrict__ F,
                            int* __restrict__ POS, int* __restrict__ ORD) {
    __shared__ unsigned int ukey[NPIX];
    int task = blockIdx.x;
    int feat = task >> 7;
    int dir = (task >> 6) & 1;
    int m = task & 63;
    const float* fr = F + feat * NIMG * NPIX + m * NPIX;
    int tid = threadIdx.x;
    for (int j = tid; j < NPIX; j += 256) {
        unsigned int b = __float_as_uint(fr[j]);
        ukey[j] = dir ? ~b : b;
    }
    __syncthreads();

    unsigned long long pki[4];
    int rank[4] = {0, 0, 0, 0};
    bool val[4];
    #pragma unroll
    for (int r = 0; r < 4; ++r) {
        int i = tid + 256 * r;
        val[r] = (i < NPIX);
        pki[r] = val[r] ? (((unsigned long long)ukey[i] << 10) | (unsigned)i) : 0ull;
    }

    const uint4* k4 = (const uint4*)ukey;
    for (int c = 0; c < NPIX / 4; ++c) {
        uint4 kv = k4[c];
        unsigned q = 4u * c;
        unsigned long long p0 = ((unsigned long long)kv.x << 10) | q;
        unsigned long long p1 = ((unsigned long long)kv.y << 10) | (q + 1);
        unsigned long long p2 = ((unsigned long long)kv.z << 10) | (q + 2);
        unsigned long long p3 = ((unsigned long long)kv.w << 10) | (q + 3);
        #pragma unroll
        for (int r = 0; r < 4; ++r) {
            rank[r] += (int)(p0 < pki[r]) + (int)(p1 < pki[r])
                     + (int)(p2 < pki[r]) + (int)(p3 < pki[r]);
        }
    }

    int* pos = POS + task * NPIX;
    int* ord = ORD + task * NPIX;
    #pragma unroll
    for (int r = 0; r < 4; ++r) {
        if (val[r]) {
            int i = tid + 256 * r;
            pos[i] = rank[r];
            ord[rank[r]] = i;
        }
    }
}

// ---------------------------------------------------------------------------
// Kernel 5: fused UF + landscape via BASIN DECOMPOSITION. One wave per task.
// (unchanged from round 11 — ballot-driven P5)
// ---------------------------------------------------------------------------
template<int NN>   // NN = 4 (dir 0) or 8 (dir 1)
__device__ int uf_basin_run(const int* posA, const int* ordA,
                            int* bas, int* comp, int* recs, int* pairsI) {
    const int lane = threadIdx.x;

    // ---- P2: forest init ----
    for (int s = lane; s < NPIX; s += 64) {
        int si = s / HW, sj = s % HW;
        int bestPos = posA[s], best = s;
        #pragma unroll
        for (int o = 0; o < NN; ++o) {
            int dx = ((DXPK >> (2 * o)) & 3) - 1;
            int dy = ((DYPK >> (2 * o)) & 3) - 1;
            int ui = si + dx, uj = sj + dy;
            if ((unsigned)ui < (unsigned)HW && (unsigned)uj < (unsigned)HW) {
                int u = ui * HW + uj;
                int pu = posA[u];
                if (pu < bestPos) { bestPos = pu; best = u; }
            }
        }
        bas[s] = best;
    }
    __syncthreads();

    // ---- P3: pointer jumping (2^10 = 1024 > max depth 783) ----
    for (int it = 0; it < 10; ++it) {
        for (int s = lane; s < NPIX; s += 64) {
            int b = bas[s];
            int bb = bas[b];
            if (bb != b) bas[s] = bb;
        }
        __syncthreads();
    }

    // ---- P4: candidate records, rank order ----
    int nrec = 0;
    for (int c = 0; c < 13; ++c) {
        int r = c * 64 + lane;
        int cnt = 0;
        int myr[NN - 1];
        int got[NN - 1];
        #pragma unroll
        for (int t = 0; t < NN - 1; ++t) { got[t] = -1; myr[t] = 0; }
        if (r > 0 && r < NPIX) {
            int v = ordA[r];
            int vi = v / HW, vj = v % HW;
            int pivot = bas[v];
            #pragma unroll
            for (int o = 0; o < NN; ++o) {
                int dx = ((DXPK >> (2 * o)) & 3) - 1;
                int dy = ((DYPK >> (2 * o)) & 3) - 1;
                int ui = vi + dx, uj = vj + dy;
                if ((unsigned)ui < (unsigned)HW && (unsigned)uj < (unsigned)HW) {
                    int u = ui * HW + uj;
                    if (posA[u] < r) {
                        int b = bas[u];
                        bool dup = (b == pivot);
                        #pragma unroll
                        for (int t = 0; t < NN - 1; ++t) dup = dup || (got[t] == b);
                        if (!dup) {
                            #pragma unroll
                            for (int t = 0; t < NN - 1; ++t)
                                if (t == cnt) { got[t] = b; myr[t] = (v << 20) | (pivot << 10) | b; }
                            cnt++;
                        }
                    }
                }
            }
        }
        // wave prefix-sum of cnt
        int p = cnt;
        for (int off = 1; off < 64; off <<= 1) {
            int t2 = __shfl_up(p, off, 64);
            if (lane >= off) p += t2;
        }
        int excl = p - cnt;
        int tot = __builtin_amdgcn_readlane(p, 63);
        #pragma unroll
        for (int t = 0; t < NN - 1; ++t)
            if (t < cnt) recs[nrec + excl + t] = myr[t];
        nrec += tot;
    }
    __syncthreads();

    // ---- P5: ballot-driven UF over records, 64-record chunks ----
    int k = 0;
    for (int base = 0; base < nrec; base += 64) {
        int idx = base + lane;
        int rec = (idx < nrec) ? recs[idx] : 0;
        int pa = (rec >> 10) & 1023, pbn = rec & 1023;
        int ka = 0, kb = 0;
        if (idx < nrec) { ka = comp[pa]; kb = comp[pbn]; }
        int remSrc = 0, remDst = 0;   // lane-distributed remap entries
        int nrem = 0;
        for (;;) {
            unsigned long long d = __ballot(ka != kb);
            if (d == 0ull) break;
            int i = (int)__ffsll((long long)d) - 1;   // lowest lane = lowest rank
            int sA = __builtin_amdgcn_readlane(ka, i);
            int sB = __builtin_amdgcn_readlane(kb, i);
            int w = min(sA, sB), l = max(sA, sB);     // uniform scalars
            int sv = __builtin_amdgcn_readlane(rec, i) >> 20;
            if (lane == 0) pairsI[k] = (l & 1023) | (sv << 10);
            k++;
            // keep ALL lanes' keys current (parallel, 2 cndmasks)
            ka = (ka == l) ? w : ka;
            kb = (kb == l) ? w : kb;
            // record remap entry for the comp[] flatten ("writelane")
            if (lane == nrem) { remSrc = l; remDst = w; }
            nrem++;
            if (nrem == 63) {              // overflow guard (rare)
                for (int s = lane; s < NPIX; s += 64) {
                    int cv = comp[s], c0 = cv;
                    for (int e = 0; e < nrem; ++e) {
                        int rs = __builtin_amdgcn_readlane(remSrc, e);
                        int rd = __builtin_amdgcn_readlane(remDst, e);
                        cv = (cv == rs) ? rd : cv;
                    }
                    if (cv != c0) comp[s] = cv;
                }
                if (idx < nrec) { ka = comp[pa]; kb = comp[pbn]; }
                nrem = 0;
            }
        }
        if (nrem > 0) {                    // flatten comp[] (ordered entries)
            for (int s = lane; s < NPIX; s += 64) {
                int cv = comp[s], c0 = cv;
                for (int e = 0; e < nrem; ++e) {
                    int rs = __builtin_amdgcn_readlane(remSrc, e);
                    int rd = __builtin_amdgcn_readlane(remDst, e);
                    cv = (cv == rs) ? rd : cv;
                }
                if (cv != c0) comp[s] = cv;
            }
        }
        __syncthreads();
    }
    return k;
}

__global__ void __launch_bounds__(64) uf_land_kernel(const int* __restrict__ POS,
                                                     const int* __restrict__ ORD,
                                                     const float* __restrict__ F,
                                                     float* __restrict__ LAM1,
                                                     float* __restrict__ LAM2) {
    __shared__ int posA[NPIX], ordA[NPIX], bas[NPIX], comp[NPIX], pairsI[NPIX];
    __shared__ float fv[NPIX];
    __shared__ float2 pairs[NPIX];
    __shared__ int recs[MAXREC];
    int lane = threadIdx.x;
    int task = blockIdx.x;
    int feat = task >> 7;
    int dir = (task >> 6) & 1;
    int m = task & 63;
    const int* gpos = POS + task * NPIX;
    const int* gord = ORD + task * NPIX;
    const float* fr = F + feat * NIMG * NPIX + m * NPIX;
    for (int s = lane; s < NPIX; s += 64) {
        int p = gpos[s];
        posA[s] = p;
        comp[s] = (p << 10) | s;   // self key (valid at basin roots)
        ordA[s] = gord[s];
        fv[s] = fr[s];
    }
    __syncthreads();

    int k;
    if (dir == 0) k = uf_basin_run<4>(posA, ordA, bas, comp, recs, pairsI);
    else          k = uf_basin_run<8>(posA, ordA, bas, comp, recs, pairsI);
    __syncthreads();

    // convert packed pairs to (b, d) float values (dir 1 stores swapped)
    for (int s = lane; s < k; s += 64) {
        int p = pairsI[s];
        float fb = fv[p & 1023], fd = fv[p >> 10];
        pairs[s] = dir ? make_float2(fd, fb) : make_float2(fb, fd);
    }
    __syncthreads();

    // ---- fused landscape: top-3 tents over the k real pairs ----
    if (lane < 32) {
        int t = lane;
        float start = (feat == 0) ? 0.f : 1.f;
        float end   = (feat == 0) ? 7.f : 8.f;
        float tv = start + (end - start) * ((float)t / 31.f);
        float v0 = 0.f, v1 = 0.f, v2 = 0.f;
        for (int p = 0; p < k; ++p) {
            float2 bd = pairs[p];
            float tent = fmaxf(fminf(tv - bd.x, bd.y - tv), 0.f);
            if (tent > v0)      { v2 = v1; v1 = v0; v0 = tent; }
            else if (tent > v1) { v2 = v1; v1 = tent; }
            else if (tent > v2) { v2 = tent; }
        }
        if (feat == 0) {
            float* lam = LAM1 + m * 128 + dir * 64;
            lam[0 * 32 + t] = v0;
            lam[1 * 32 + t] = v1;
        } else {
            float* lam = LAM2 + m * 192 + dir * 96;
            lam[0 * 32 + t] = v0;
            lam[1 * 32 + t] = v1;
            lam[2 * 32 + t] = v2;
        }
    }
}

// ---------------------------------------------------------------------------
// Kernel 6: MLP head. One block (64 threads) per image.
// ---------------------------------------------------------------------------
__global__ void mlp_kernel(const float* __restrict__ LAM1, const float* __restrict__ LAM2,
                           const float* __restrict__ w1, const float* __restrict__ b1,
                           const float* __restrict__ w2, const float* __restrict__ b2,
                           const float* __restrict__ wf, const float* __restrict__ bf,
                           float* __restrict__ out) {
    __shared__ float xc[64];
    int m = blockIdx.x;
    int n = threadIdx.x;
    if (n < 32) {
        float acc = b1[n];
        const float* l = LAM1 + m * 128;
        for (int c = 0; c < 128; ++c) acc += w1[n * 128 + c] * l[c];
        xc[n] = fmaxf(acc, 0.f);
    } else {
        int n2 = n - 32;
        float acc = b2[n2];
        const float* l = LAM2 + m * 192;
        for (int c = 0; c < 192; ++c) acc += w2[n2 * 192 + c] * l[c];
        xc[n] = fmaxf(acc, 0.f);
    }
    __syncthreads();
    if (n < 10) {
        float acc = bf[n];
        for (int c = 0; c < 64; ++c) acc += wf[n * 64 + c] * xc[c];
        out[m * 10 + n] = acc;
    }
}

extern "C" void kernel_launch(void* const* d_in, const int* in_sizes, int n_in,
                              void* d_out, int out_size, void* d_ws, size_t ws_size,
                              hipStream_t stream) {
    const float* x  = (const float*)d_in[0];
    const float* w1 = (const float*)d_in[1];
    const float* b1 = (const float*)d_in[2];
    const float* w2 = (const float*)d_in[3];
    const float* b2 = (const float*)d_in[4];
    const float* wf = (const float*)d_in[5];
    const float* bf = (const float*)d_in[6];
    float* out = (float*)d_out;

    char* ws = (char*)d_ws;
    size_t off = 0;
    unsigned short* SORT = (unsigned short*)(ws + off); off += (size_t)NPIX * NPIX * 2;
    unsigned short* D2S  = (unsigned short*)(ws + off); off += (size_t)NPIX * NPIX * 2;
    float* SUMS = (float*)(ws + off); off += 256;
    float* F    = (float*)(ws + off); off += (size_t)2 * NIMG * NPIX * 4;
    int* POS    = (int*)(ws + off);   off += (size_t)256 * NPIX * 4;
    int* ORD    = (int*)(ws + off);   off += (size_t)256 * NPIX * 4;
    float* LAM1 = (float*)(ws + off); off += (size_t)NIMG * 128 * 4;
    float* LAM2 = (float*)(ws + off); off += (size_t)NIMG * 192 * 4;

    build_consts_kernel<<<NPIX, 256, 0, stream>>>(SORT, D2S);
    row_sum_kernel<<<NIMG, 256, 0, stream>>>(x, SUMS);
    dtm_kernel<<<(NIMG * NPIX) / 4, 256, 0, stream>>>(x, SORT, D2S, SUMS, F);
    rank_kernel<<<256, 256, 0, stream>>>(F, POS, ORD);
    uf_land_kernel<<<256, 64, 0, stream>>>(POS, ORD, F, LAM1, LAM2);
    mlp_kernel<<<NIMG, 64, 0, stream>>>(LAM1, LAM2, w1, b1, w2, b2, wf, bf, out);
}

// Round 13
// 155.374 us; speedup vs baseline: 2.3355x; 1.2953x over previous
//
#include <hip/hip_runtime.h>

#define HW 28
#define NPIX 784   // 28*28
#define NIMG 64
#define MAXD2 1459 // d2 <= 2*27^2 = 1458
#define MAXREC 5504  // 783 * 7 worst case

// packed dx/dy (+1, 2 bits each) for {-1,0},{1,0},{0,-1},{0,1},
// {-1,-1},{-1,1},{1,-1},{1,1}; first 4 = 4-connectivity
#define DXPK 41048u
#define DYPK 34949u

// ---------------------------------------------------------------------------
// Kernel 1: grid distance-sort constants via LDS counting sort.
// ---------------------------------------------------------------------------
__global__ void build_consts_kernel(unsigned short* __restrict__ sortIdx,
                                    unsigned short* __restrict__ d2s) {
    __shared__ int cnt[MAXD2];
    __shared__ int d2v[NPIX];
    __shared__ int wtot[4];
    int i = blockIdx.x;
    int tid = threadIdx.x;
    for (int b = tid; b < MAXD2; b += 256) cnt[b] = 0;
    __syncthreads();
    int ii = i / HW, ij = i % HW;
    for (int j = tid; j < NPIX; j += 256) {
        int di = ii - j / HW, dj = ij - j % HW;
        int d = di * di + dj * dj;
        d2v[j] = d;
        atomicAdd(&cnt[d], 1);
    }
    __syncthreads();
    int b0 = tid * 6;
    int lc[6];
    int s0 = 0;
    #pragma unroll
    for (int t = 0; t < 6; ++t) {
        int b = b0 + t;
        lc[t] = (b < MAXD2) ? cnt[b] : 0;
        s0 += lc[t];
    }
    int lane = tid & 63, wv = tid >> 6;
    int v = s0;
    for (int off = 1; off < 64; off <<= 1) {
        int t2 = __shfl_up(v, off, 64);
        if (lane >= off) v += t2;
    }
    if (lane == 63) wtot[wv] = v;
    __syncthreads();
    int wadd = 0;
    for (int w2 = 0; w2 < wv; ++w2) wadd += wtot[w2];
    int run = wadd + v - s0;
    __syncthreads();
    #pragma unroll
    for (int t = 0; t < 6; ++t) {
        int b = b0 + t;
        if (b < MAXD2) { cnt[b] = run; run += lc[t]; }
    }
    __syncthreads();
    for (int j = tid; j < NPIX; j += 256) {
        int d = d2v[j];
        int slot = atomicAdd(&cnt[d], 1);
        sortIdx[i * NPIX + slot] = (unsigned short)j;
        d2s[i * NPIX + slot] = (unsigned short)d;
    }
}

// ---------------------------------------------------------------------------
// Kernel 2: per-image sums.
// ---------------------------------------------------------------------------
__global__ void row_sum_kernel(const float* __restrict__ x, float* __restrict__ sums) {
    int m = blockIdx.x;
    float acc = 0.f;
    for (int j = threadIdx.x; j < NPIX; j += blockDim.x) acc += x[m * NPIX + j];
    for (int off = 32; off > 0; off >>= 1) acc += __shfl_down(acc, off, 64);
    __shared__ float red[4];
    int lane = threadIdx.x & 63, w = threadIdx.x >> 6;
    if (lane == 0) red[w] = acc;
    __syncthreads();
    if (threadIdx.x == 0) sums[m] = red[0] + red[1] + red[2] + red[3];
}

// ---------------------------------------------------------------------------
// Kernel 3: DTM. One wave per (m, i). Early exit once cum >= bound2.
// ---------------------------------------------------------------------------
__global__ void dtm_kernel(const float* __restrict__ x,
                           const unsigned short* __restrict__ sortIdx,
                           const unsigned short* __restrict__ d2s,
                           const float* __restrict__ sums,
                           float* __restrict__ F) {
    int wid = blockIdx.x * 4 + (threadIdx.x >> 6);
    int lane = threadIdx.x & 63;
    int m = wid / NPIX;
    int i = wid % NPIX;
    if (m >= NIMG) return;
    float s = sums[m];
    float bound1 = 0.05f * s, bound2 = 0.2f * s;
    const float* xr = x + m * NPIX;
    const unsigned short* si = sortIdx + (size_t)i * NPIX;
    const unsigned short* dr = d2s + (size_t)i * NPIX;
    float carry = 0.f, acc1 = 0.f, acc2 = 0.f;
    for (int c = 0; c < 7; ++c) {
        int j0 = c * 128 + lane * 2;
        float w0 = 0.f, w1 = 0.f, d0 = 0.f, d1 = 0.f;
        if (j0 < NPIX) {
            ushort2 sv = *(const ushort2*)(si + j0);
            ushort2 dv = *(const ushort2*)(dr + j0);
            w0 = xr[sv.x]; w1 = xr[sv.y];
            d0 = (float)dv.x; d1 = (float)dv.y;
        }
        float ps = w0 + w1;
        float v = ps;
        for (int off = 1; off < 64; off <<= 1) {
            float t = __shfl_up(v, off, 64);
            if (lane >= off) v += t;
        }
        float cum0 = carry + v - ps;
        float cum1 = cum0 + w0;
        acc1 += fminf(fmaxf(bound1 - cum0, 0.f), w0) * d0
              + fminf(fmaxf(bound1 - cum1, 0.f), w1) * d1;
        acc2 += fminf(fmaxf(bound2 - cum0, 0.f), w0) * d0
              + fminf(fmaxf(bound2 - cum1, 0.f), w1) * d1;
        carry += __shfl(v, 63, 64);
        if (carry >= bound2) break;   // wave-uniform: all later eff == 0
    }
    for (int off = 32; off > 0; off >>= 1) {
        acc1 += __shfl_down(acc1, off, 64);
        acc2 += __shfl_down(acc2, off, 64);
    }
    if (lane == 0) {
        F[0 * NIMG * NPIX + m * NPIX + i] = sqrtf(acc1 / bound1);
        F[1 * NIMG * NPIX + m * NPIX + i] = sqrtf(acc2 / bound2);
    }
}

// ---------------------------------------------------------------------------
// Kernel 4: fused RANK + UF (basin decomposition) + LANDSCAPE.
// One 256-thread block per task (4 waves).
//  Rank: register-blocked counting with dir-adjusted IEEE-bit keys (values
//        >= 0 so bits are order-isomorphic); exact stable tie-break via
//        packed u64 (key<<10|idx). POS/ORD stay in LDS — no global trip.
//  P2: steepest-descent forest; P3: 10 pointer-jump passes (256-wide);
//  P4: candidate saddle records in rank order, block-wide scan compaction;
//  P5: wave-0 ballot-driven serial resolution (merge entries to LDS);
//      comp[] flatten by all 256 threads. Winner = min packed key.
// Pair SET == reference's nonzero-persistence set (order-invariant elder
// rule; (v,v) self pairs and (0,0) padding have tent == 0).
// ---------------------------------------------------------------------------
template<int NN>   // NN = 4 (dir 0) or 8 (dir 1)
__device__ int uf_basin_run(const int* posA, const int* ordA,
                            int* bas, int* comp, int* recs, int* pairsI,
                            int2* mergeLDS, int* shInts, int* wtot4) {
    const int tid = threadIdx.x;
    const int lane = tid & 63, wv = tid >> 6;

    // ---- P2: steepest-descent forest ----
    for (int s = tid; s < NPIX; s += 256) {
        int si = s / HW, sj = s % HW;
        int bestPos = posA[s], best = s;
        #pragma unroll
        for (int o = 0; o < NN; ++o) {
            int dx = ((DXPK >> (2 * o)) & 3) - 1;
            int dy = ((DYPK >> (2 * o)) & 3) - 1;
            int ui = si + dx, uj = sj + dy;
            if ((unsigned)ui < (unsigned)HW && (unsigned)uj < (unsigned)HW) {
                int u = ui * HW + uj;
                int pu = posA[u];
                if (pu < bestPos) { bestPos = pu; best = u; }
            }
        }
        bas[s] = best;
    }
    __syncthreads();

    // ---- P3: pointer jumping (2^10 = 1024 > max depth 783) ----
    for (int it = 0; it < 10; ++it) {
        for (int s = tid; s < NPIX; s += 256) {
            int b = bas[s];
            int bb = bas[b];
            if (bb != b) bas[s] = bb;
        }
        __syncthreads();
    }

    // ---- P4: candidate records in rank order, block-scan compaction ----
    int nrec = 0;
    for (int c = 0; c < 4; ++c) {
        int r = c * 256 + tid;
        int cnt = 0;
        int myr[NN - 1];
        int got[NN - 1];
        #pragma unroll
        for (int t = 0; t < NN - 1; ++t) { got[t] = -1; myr[t] = 0; }
        if (r > 0 && r < NPIX) {
            int v = ordA[r];
            int vi = v / HW, vj = v % HW;
            int pivot = bas[v];
            #pragma unroll
            for (int o = 0; o < NN; ++o) {
                int dx = ((DXPK >> (2 * o)) & 3) - 1;
                int dy = ((DYPK >> (2 * o)) & 3) - 1;
                int ui = vi + dx, uj = vj + dy;
                if ((unsigned)ui < (unsigned)HW && (unsigned)uj < (unsigned)HW) {
                    int u = ui * HW + uj;
                    if (posA[u] < r) {
                        int b = bas[u];
                        bool dup = (b == pivot);
                        #pragma unroll
                        for (int t = 0; t < NN - 1; ++t) dup = dup || (got[t] == b);
                        if (!dup) {
                            #pragma unroll
                            for (int t = 0; t < NN - 1; ++t)
                                if (t == cnt) { got[t] = b; myr[t] = (v << 20) | (pivot << 10) | b; }
                            cnt++;
                        }
                    }
                }
            }
        }
        // block-wide exclusive prefix of cnt
        int p = cnt;
        for (int off = 1; off < 64; off <<= 1) {
            int t2 = __shfl_up(p, off, 64);
            if (lane >= off) p += t2;
        }
        if (lane == 63) wtot4[wv] = p;
        __syncthreads();
        int wadd = 0;
        for (int w2 = 0; w2 < wv; ++w2) wadd += wtot4[w2];
        int tot = wtot4[0] + wtot4[1] + wtot4[2] + wtot4[3];
        int excl = wadd + p - cnt;
        #pragma unroll
        for (int t = 0; t < NN - 1; ++t)
            if (t < cnt) recs[nrec + excl + t] = myr[t];
        nrec += tot;
        __syncthreads();
    }

    // ---- P5: ballot-driven serial UF (wave 0), block-wide flatten ----
    int k = 0;
    for (int base = 0; base < nrec; base += 64) {
        int nrem = 0;
        if (wv == 0) {
            int idx = base + lane;
            int rec = (idx < nrec) ? recs[idx] : 0;
            int pa = (rec >> 10) & 1023, pbn = rec & 1023;
            int ka = 0, kb = 0;
            if (idx < nrec) { ka = comp[pa]; kb = comp[pbn]; }
            for (;;) {
                unsigned long long d = __ballot(ka != kb);
                if (d == 0ull) break;
                int i = (int)__ffsll((long long)d) - 1;   // lowest lane = lowest rank
                int sA = __builtin_amdgcn_readlane(ka, i);
                int sB = __builtin_amdgcn_readlane(kb, i);
                int w = min(sA, sB), l = max(sA, sB);     // uniform scalars
                int sv = __builtin_amdgcn_readlane(rec, i) >> 20;
                if (lane == 0) {
                    pairsI[k] = (l & 1023) | (sv << 10);
                    mergeLDS[nrem] = make_int2(l, w);
                }
                k++;
                ka = (ka == l) ? w : ka;
                kb = (kb == l) ? w : kb;
                nrem++;
                if (nrem == 63) {              // overflow guard (rare): wave-0 flatten
                    for (int s = lane; s < NPIX; s += 64) {
                        int cv = comp[s], c0 = cv;
                        for (int e = 0; e < nrem; ++e) {
                            int2 me = mergeLDS[e];
                            cv = (cv == me.x) ? me.y : cv;
                        }
                        if (cv != c0) comp[s] = cv;
                    }
                    if (idx < nrec) { ka = comp[pa]; kb = comp[pbn]; }
                    nrem = 0;
                }
            }
            if (lane == 0) shInts[0] = nrem;
        }
        __syncthreads();
        int nr = shInts[0];
        if (nr > 0) {                          // flatten with all 256 threads
            for (int s = tid; s < NPIX; s += 256) {
                int cv = comp[s], c0 = cv;
                for (int e = 0; e < nr; ++e) {
                    int2 me = mergeLDS[e];
                    cv = (cv == me.x) ? me.y : cv;
                }
                if (cv != c0) comp[s] = cv;
            }
        }
        __syncthreads();
    }
    if (tid == 0) shInts[1] = k;
    __syncthreads();
    return shInts[1];
}

__global__ void __launch_bounds__(256) uf_land_kernel(const float* __restrict__ F,
                                                      float* __restrict__ LAM1,
                                                      float* __restrict__ LAM2) {
    __shared__ int posA[NPIX], ordA[NPIX], bas[NPIX], comp[NPIX], pairsI[NPIX];
    __shared__ unsigned int ukey[NPIX];
    __shared__ float fv[NPIX];
    __shared__ float2 pairs[NPIX];
    __shared__ int recs[MAXREC];
    __shared__ int2 mergeLDS[64];
    __shared__ int shInts[2];
    __shared__ int wtot4[4];
    int tid = threadIdx.x;
    int task = blockIdx.x;
    int feat = task >> 7;
    int dir = (task >> 6) & 1;
    int m = task & 63;
    const float* fr = F + feat * NIMG * NPIX + m * NPIX;

    // load values + dir-adjusted sortable keys
    for (int j = tid; j < NPIX; j += 256) {
        float f = fr[j];
        fv[j] = f;
        unsigned int b = __float_as_uint(f);
        ukey[j] = dir ? ~b : b;
    }
    __syncthreads();

    // ---- fused rank (register-blocked, b128 LDS reads, u64 packed keys) ----
    {
        unsigned long long pki[4];
        int rank[4] = {0, 0, 0, 0};
        bool val[4];
        #pragma unroll
        for (int r = 0; r < 4; ++r) {
            int i = tid + 256 * r;
            val[r] = (i < NPIX);
            pki[r] = val[r] ? (((unsigned long long)ukey[i] << 10) | (unsigned)i) : 0ull;
        }
        const uint4* k4 = (const uint4*)ukey;
        for (int c = 0; c < NPIX / 4; ++c) {
            uint4 kv = k4[c];
            unsigned q = 4u * c;
            unsigned long long p0 = ((unsigned long long)kv.x << 10) | q;
            unsigned long long p1 = ((unsigned long long)kv.y << 10) | (q + 1);
            unsigned long long p2 = ((unsigned long long)kv.z << 10) | (q + 2);
            unsigned long long p3 = ((unsigned long long)kv.w << 10) | (q + 3);
            #pragma unroll
            for (int r = 0; r < 4; ++r) {
                rank[r] += (int)(p0 < pki[r]) + (int)(p1 < pki[r])
                         + (int)(p2 < pki[r]) + (int)(p3 < pki[r]);
            }
        }
        #pragma unroll
        for (int r = 0; r < 4; ++r) {
            if (val[r]) {
                int i = tid + 256 * r;
                posA[i] = rank[r];
                ordA[rank[r]] = i;
            }
        }
    }
    __syncthreads();
    for (int s = tid; s < NPIX; s += 256) comp[s] = (posA[s] << 10) | s;
    // (comp init needs no barrier before P2: P2 reads only posA)

    int k;
    if (dir == 0) k = uf_basin_run<4>(posA, ordA, bas, comp, recs, pairsI,
                                      mergeLDS, shInts, wtot4);
    else          k = uf_basin_run<8>(posA, ordA, bas, comp, recs, pairsI,
                                      mergeLDS, shInts, wtot4);

    // convert packed pairs to (b, d) float values (dir 1 stores swapped)
    for (int s = tid; s < k; s += 256) {
        int p = pairsI[s];
        float fb = fv[p & 1023], fd = fv[p >> 10];
        pairs[s] = dir ? make_float2(fd, fb) : make_float2(fb, fd);
    }
    __syncthreads();

    // ---- fused landscape: top-3 tents over the k real pairs ----
    if (tid < 32) {
        int t = tid;
        float start = (feat == 0) ? 0.f : 1.f;
        float end   = (feat == 0) ? 7.f : 8.f;
        float tv = start + (end - start) * ((float)t / 31.f);
        float v0 = 0.f, v1 = 0.f, v2 = 0.f;
        for (int p = 0; p < k; ++p) {
            float2 bd = pairs[p];
            float tent = fmaxf(fminf(tv - bd.x, bd.y - tv), 0.f);
            if (tent > v0)      { v2 = v1; v1 = v0; v0 = tent; }
            else if (tent > v1) { v2 = v1; v1 = tent; }
            else if (tent > v2) { v2 = tent; }
        }
        if (feat == 0) {
            float* lam = LAM1 + m * 128 + dir * 64;
            lam[0 * 32 + t] = v0;
            lam[1 * 32 + t] = v1;
        } else {
            float* lam = LAM2 + m * 192 + dir * 96;
            lam[0 * 32 + t] = v0;
            lam[1 * 32 + t] = v1;
            lam[2 * 32 + t] = v2;
        }
    }
}

// ---------------------------------------------------------------------------
// Kernel 5: MLP head. One block (64 threads) per image.
// ---------------------------------------------------------------------------
__global__ void mlp_kernel(const float* __restrict__ LAM1, const float* __restrict__ LAM2,
                           const float* __restrict__ w1, const float* __restrict__ b1,
                           const float* __restrict__ w2, const float* __restrict__ b2,
                           const float* __restrict__ wf, const float* __restrict__ bf,
                           float* __restrict__ out) {
    __shared__ float xc[64];
    int m = blockIdx.x;
    int n = threadIdx.x;
    if (n < 32) {
        float acc = b1[n];
        const float* l = LAM1 + m * 128;
        for (int c = 0; c < 128; ++c) acc += w1[n * 128 + c] * l[c];
        xc[n] = fmaxf(acc, 0.f);
    } else {
        int n2 = n - 32;
        float acc = b2[n2];
        const float* l = LAM2 + m * 192;
        for (int c = 0; c < 192; ++c) acc += w2[n2 * 192 + c] * l[c];
        xc[n] = fmaxf(acc, 0.f);
    }
    __syncthreads();
    if (n < 10) {
        float acc = bf[n];
        for (int c = 0; c < 64; ++c) acc += wf[n * 64 + c] * xc[c];
        out[m * 10 + n] = acc;
    }
}

extern "C" void kernel_launch(void* const* d_in, const int* in_sizes, int n_in,
                              void* d_out, int out_size, void* d_ws, size_t ws_size,
                              hipStream_t stream) {
    const float* x  = (const float*)d_in[0];
    const float* w1 = (const float*)d_in[1];
    const float* b1 = (const float*)d_in[2];
    const float* w2 = (const float*)d_in[3];
    const float* b2 = (const float*)d_in[4];
    const float* wf = (const float*)d_in[5];
    const float* bf = (const float*)d_in[6];
    float* out = (float*)d_out;

    char* ws = (char*)d_ws;
    size_t off = 0;
    unsigned short* SORT = (unsigned short*)(ws + off); off += (size_t)NPIX * NPIX * 2;
    unsigned short* D2S  = (unsigned short*)(ws + off); off += (size_t)NPIX * NPIX * 2;
    float* SUMS = (float*)(ws + off); off += 256;
    float* F    = (float*)(ws + off); off += (size_t)2 * NIMG * NPIX * 4;
    float* LAM1 = (float*)(ws + off); off += (size_t)NIMG * 128 * 4;
    float* LAM2 = (float*)(ws + off); off += (size_t)NIMG * 192 * 4;

    build_consts_kernel<<<NPIX, 256, 0, stream>>>(SORT, D2S);
    row_sum_kernel<<<NIMG, 256, 0, stream>>>(x, SUMS);
    dtm_kernel<<<(NIMG * NPIX) / 4, 256, 0, stream>>>(x, SORT, D2S, SUMS, F);
    uf_land_kernel<<<256, 256, 0, stream>>>(F, LAM1, LAM2);
    mlp_kernel<<<NIMG, 64, 0, stream>>>(LAM1, LAM2, w1, b1, w2, b2, wf, bf, out);
}

// Round 14
// 147.552 us; speedup vs baseline: 2.4594x; 1.0530x over previous
//
#include <hip/hip_runtime.h>

#define HW 28
#define NPIX 784   // 28*28
#define NIMG 64
#define MAXD2 1459 // d2 <= 2*27^2 = 1458
#define MAXREC 5504  // 783 * 7 worst case

// packed dx/dy (+1, 2 bits each) for {-1,0},{1,0},{0,-1},{0,1},
// {-1,-1},{-1,1},{1,-1},{1,1}; first 4 = 4-connectivity
#define DXPK 41048u
#define DYPK 34949u

// ---------------------------------------------------------------------------
// Kernel 1: grid distance-sort constants (counting sort) + per-image sums
// fused into one dispatch (blocks [0,784) = consts, [784,848) = sums).
// ---------------------------------------------------------------------------
__global__ void consts_sums_kernel(unsigned short* __restrict__ sortIdx,
                                   unsigned short* __restrict__ d2s,
                                   const float* __restrict__ x,
                                   float* __restrict__ sums) {
    int tid = threadIdx.x;
    if (blockIdx.x >= NPIX) {
        // ---- row sum for image m ----
        int m = blockIdx.x - NPIX;
        float acc = 0.f;
        for (int j = tid; j < NPIX; j += 256) acc += x[m * NPIX + j];
        for (int off = 32; off > 0; off >>= 1) acc += __shfl_down(acc, off, 64);
        __shared__ float red[4];
        int lane = tid & 63, w = tid >> 6;
        if (lane == 0) red[w] = acc;
        __syncthreads();
        if (tid == 0) sums[m] = red[0] + red[1] + red[2] + red[3];
        return;
    }
    __shared__ int cnt[MAXD2];
    __shared__ int d2v[NPIX];
    __shared__ int wtot[4];
    int i = blockIdx.x;
    for (int b = tid; b < MAXD2; b += 256) cnt[b] = 0;
    __syncthreads();
    int ii = i / HW, ij = i % HW;
    for (int j = tid; j < NPIX; j += 256) {
        int di = ii - j / HW, dj = ij - j % HW;
        int d = di * di + dj * dj;
        d2v[j] = d;
        atomicAdd(&cnt[d], 1);
    }
    __syncthreads();
    int b0 = tid * 6;
    int lc[6];
    int s0 = 0;
    #pragma unroll
    for (int t = 0; t < 6; ++t) {
        int b = b0 + t;
        lc[t] = (b < MAXD2) ? cnt[b] : 0;
        s0 += lc[t];
    }
    int lane = tid & 63, wv = tid >> 6;
    int v = s0;
    for (int off = 1; off < 64; off <<= 1) {
        int t2 = __shfl_up(v, off, 64);
        if (lane >= off) v += t2;
    }
    if (lane == 63) wtot[wv] = v;
    __syncthreads();
    int wadd = 0;
    for (int w2 = 0; w2 < wv; ++w2) wadd += wtot[w2];
    int run = wadd + v - s0;
    __syncthreads();
    #pragma unroll
    for (int t = 0; t < 6; ++t) {
        int b = b0 + t;
        if (b < MAXD2) { cnt[b] = run; run += lc[t]; }
    }
    __syncthreads();
    for (int j = tid; j < NPIX; j += 256) {
        int d = d2v[j];
        int slot = atomicAdd(&cnt[d], 1);
        sortIdx[i * NPIX + slot] = (unsigned short)j;
        d2s[i * NPIX + slot] = (unsigned short)d;
    }
}

// ---------------------------------------------------------------------------
// Kernel 2: DTM. One wave per (m, i). 4 elems/lane (256-elem chunks) — the
// first chunk nearly always reaches bound2 (0.2*sum ~ 160 sorted nbrs), so
// typically ONE scan. Early exit exact: all later eff terms are 0.
// ---------------------------------------------------------------------------
__global__ void dtm_kernel(const float* __restrict__ x,
                           const unsigned short* __restrict__ sortIdx,
                           const unsigned short* __restrict__ d2s,
                           const float* __restrict__ sums,
                           float* __restrict__ F) {
    int wid = blockIdx.x * 4 + (threadIdx.x >> 6);
    int lane = threadIdx.x & 63;
    int m = wid / NPIX;
    int i = wid % NPIX;
    if (m >= NIMG) return;
    float s = sums[m];
    float bound1 = 0.05f * s, bound2 = 0.2f * s;
    const float* xr = x + m * NPIX;
    const unsigned short* si = sortIdx + (size_t)i * NPIX;
    const unsigned short* dr = d2s + (size_t)i * NPIX;
    float carry = 0.f, acc1 = 0.f, acc2 = 0.f;
    for (int c = 0; c < 4; ++c) {           // 4*256 = 1024 >= 784
        int j0 = c * 256 + lane * 4;        // 784 % 4 == 0: all-or-nothing
        float w0 = 0.f, w1 = 0.f, w2 = 0.f, w3 = 0.f;
        float d0 = 0.f, d1 = 0.f, d2 = 0.f, d3 = 0.f;
        if (j0 < NPIX) {
            ushort4 sv = *(const ushort4*)(si + j0);
            ushort4 dv = *(const ushort4*)(dr + j0);
            w0 = xr[sv.x]; w1 = xr[sv.y]; w2 = xr[sv.z]; w3 = xr[sv.w];
            d0 = (float)dv.x; d1 = (float)dv.y; d2 = (float)dv.z; d3 = (float)dv.w;
        }
        float ps = w0 + w1 + w2 + w3;
        float v = ps;
        for (int off = 1; off < 64; off <<= 1) {
            float t = __shfl_up(v, off, 64);
            if (lane >= off) v += t;
        }
        float c0 = carry + v - ps;          // exclusive prefix before elem0
        float c1 = c0 + w0, c2 = c1 + w1, c3 = c2 + w2;
        acc1 += fminf(fmaxf(bound1 - c0, 0.f), w0) * d0
              + fminf(fmaxf(bound1 - c1, 0.f), w1) * d1
              + fminf(fmaxf(bound1 - c2, 0.f), w2) * d2
              + fminf(fmaxf(bound1 - c3, 0.f), w3) * d3;
        acc2 += fminf(fmaxf(bound2 - c0, 0.f), w0) * d0
              + fminf(fmaxf(bound2 - c1, 0.f), w1) * d1
              + fminf(fmaxf(bound2 - c2, 0.f), w2) * d2
              + fminf(fmaxf(bound2 - c3, 0.f), w3) * d3;
        carry += __shfl(v, 63, 64);
        if (carry >= bound2) break;         // wave-uniform: later eff == 0
    }
    for (int off = 32; off > 0; off >>= 1) {
        acc1 += __shfl_down(acc1, off, 64);
        acc2 += __shfl_down(acc2, off, 64);
    }
    if (lane == 0) {
        F[0 * NIMG * NPIX + m * NPIX + i] = sqrtf(acc1 / bound1);
        F[1 * NIMG * NPIX + m * NPIX + i] = sqrtf(acc2 / bound2);
    }
}

// ---------------------------------------------------------------------------
// Kernel 3: fused RANK + UF (basin decomposition) + LANDSCAPE.
// One 256-thread block per task. P3 now exits on convergence
// (__syncthreads_count == 0 => no writes that pass => fully flattened).
// ---------------------------------------------------------------------------
template<int NN>   // NN = 4 (dir 0) or 8 (dir 1)
__device__ int uf_basin_run(const int* posA, const int* ordA,
                            int* bas, int* comp, int* recs, int* pairsI,
                            int2* mergeLDS, int* shInts, int* wtot4) {
    const int tid = threadIdx.x;
    const int lane = tid & 63, wv = tid >> 6;

    // ---- P2: steepest-descent forest ----
    for (int s = tid; s < NPIX; s += 256) {
        int si = s / HW, sj = s % HW;
        int bestPos = posA[s], best = s;
        #pragma unroll
        for (int o = 0; o < NN; ++o) {
            int dx = ((DXPK >> (2 * o)) & 3) - 1;
            int dy = ((DYPK >> (2 * o)) & 3) - 1;
            int ui = si + dx, uj = sj + dy;
            if ((unsigned)ui < (unsigned)HW && (unsigned)uj < (unsigned)HW) {
                int u = ui * HW + uj;
                int pu = posA[u];
                if (pu < bestPos) { bestPos = pu; best = u; }
            }
        }
        bas[s] = best;
    }
    __syncthreads();

    // ---- P3: pointer jumping with convergence early-exit ----
    for (int it = 0; it < 10; ++it) {
        int changed = 0;
        for (int s = tid; s < NPIX; s += 256) {
            int b = bas[s];
            int bb = bas[b];
            if (bb != b) { bas[s] = bb; changed = 1; }
        }
        if (__syncthreads_count(changed) == 0) break;
    }

    // ---- P4: candidate records in rank order, block-scan compaction ----
    int nrec = 0;
    for (int c = 0; c < 4; ++c) {
        int r = c * 256 + tid;
        int cnt = 0;
        int myr[NN - 1];
        int got[NN - 1];
        #pragma unroll
        for (int t = 0; t < NN - 1; ++t) { got[t] = -1; myr[t] = 0; }
        if (r > 0 && r < NPIX) {
            int v = ordA[r];
            int vi = v / HW, vj = v % HW;
            int pivot = bas[v];
            #pragma unroll
            for (int o = 0; o < NN; ++o) {
                int dx = ((DXPK >> (2 * o)) & 3) - 1;
                int dy = ((DYPK >> (2 * o)) & 3) - 1;
                int ui = vi + dx, uj = vj + dy;
                if ((unsigned)ui < (unsigned)HW && (unsigned)uj < (unsigned)HW) {
                    int u = ui * HW + uj;
                    if (posA[u] < r) {
                        int b = bas[u];
                        bool dup = (b == pivot);
                        #pragma unroll
                        for (int t = 0; t < NN - 1; ++t) dup = dup || (got[t] == b);
                        if (!dup) {
                            #pragma unroll
                            for (int t = 0; t < NN - 1; ++t)
                                if (t == cnt) { got[t] = b; myr[t] = (v << 20) | (pivot << 10) | b; }
                            cnt++;
                        }
                    }
                }
            }
        }
        // block-wide exclusive prefix of cnt
        int p = cnt;
        for (int off = 1; off < 64; off <<= 1) {
            int t2 = __shfl_up(p, off, 64);
            if (lane >= off) p += t2;
        }
        if (lane == 63) wtot4[wv] = p;
        __syncthreads();
        int wadd = 0;
        for (int w2 = 0; w2 < wv; ++w2) wadd += wtot4[w2];
        int tot = wtot4[0] + wtot4[1] + wtot4[2] + wtot4[3];
        int excl = wadd + p - cnt;
        #pragma unroll
        for (int t = 0; t < NN - 1; ++t)
            if (t < cnt) recs[nrec + excl + t] = myr[t];
        nrec += tot;
        __syncthreads();
    }

    // ---- P5: ballot-driven serial UF (wave 0), block-wide flatten ----
    int k = 0;
    for (int base = 0; base < nrec; base += 64) {
        int nrem = 0;
        if (wv == 0) {
            int idx = base + lane;
            int rec = (idx < nrec) ? recs[idx] : 0;
            int pa = (rec >> 10) & 1023, pbn = rec & 1023;
            int ka = 0, kb = 0;
            if (idx < nrec) { ka = comp[pa]; kb = comp[pbn]; }
            for (;;) {
                unsigned long long d = __ballot(ka != kb);
                if (d == 0ull) break;
                int i = (int)__ffsll((long long)d) - 1;   // lowest lane = lowest rank
                int sA = __builtin_amdgcn_readlane(ka, i);
                int sB = __builtin_amdgcn_readlane(kb, i);
                int w = min(sA, sB), l = max(sA, sB);     // uniform scalars
                int sv = __builtin_amdgcn_readlane(rec, i) >> 20;
                if (lane == 0) {
                    pairsI[k] = (l & 1023) | (sv << 10);
                    mergeLDS[nrem] = make_int2(l, w);
                }
                k++;
                ka = (ka == l) ? w : ka;
                kb = (kb == l) ? w : kb;
                nrem++;
                if (nrem == 63) {              // overflow guard (rare): wave-0 flatten
                    for (int s = lane; s < NPIX; s += 64) {
                        int cv = comp[s], c0 = cv;
                        for (int e = 0; e < nrem; ++e) {
                            int2 me = mergeLDS[e];
                            cv = (cv == me.x) ? me.y : cv;
                        }
                        if (cv != c0) comp[s] = cv;
                    }
                    if (idx < nrec) { ka = comp[pa]; kb = comp[pbn]; }
                    nrem = 0;
                }
            }
            if (lane == 0) shInts[0] = nrem;
        }
        __syncthreads();
        int nr = shInts[0];
        if (nr > 0) {                          // flatten with all 256 threads
            for (int s = tid; s < NPIX; s += 256) {
                int cv = comp[s], c0 = cv;
                for (int e = 0; e < nr; ++e) {
                    int2 me = mergeLDS[e];
                    cv = (cv == me.x) ? me.y : cv;
                }
                if (cv != c0) comp[s] = cv;
            }
        }
        __syncthreads();
    }
    if (tid == 0) shInts[1] = k;
    __syncthreads();
    return shInts[1];
}

__global__ void __launch_bounds__(256) uf_land_kernel(const float* __restrict__ F,
                                                      float* __restrict__ LAM1,
                                                      float* __restrict__ LAM2) {
    __shared__ int posA[NPIX], ordA[NPIX], bas[NPIX], comp[NPIX], pairsI[NPIX];
    __shared__ unsigned int ukey[NPIX];
    __shared__ float fv[NPIX];
    __shared__ float2 pairs[NPIX];
    __shared__ int recs[MAXREC];
    __shared__ int2 mergeLDS[64];
    __shared__ int shInts[2];
    __shared__ int wtot4[4];
    int tid = threadIdx.x;
    int task = blockIdx.x;
    int feat = task >> 7;
    int dir = (task >> 6) & 1;
    int m = task & 63;
    const float* fr = F + feat * NIMG * NPIX + m * NPIX;

    // load values + dir-adjusted sortable keys (values >= 0: bits monotone)
    for (int j = tid; j < NPIX; j += 256) {
        float f = fr[j];
        fv[j] = f;
        unsigned int b = __float_as_uint(f);
        ukey[j] = dir ? ~b : b;
    }
    __syncthreads();

    // ---- fused rank (register-blocked, b128 LDS reads, u64 packed keys) ----
    {
        unsigned long long pki[4];
        int rank[4] = {0, 0, 0, 0};
        bool val[4];
        #pragma unroll
        for (int r = 0; r < 4; ++r) {
            int i = tid + 256 * r;
            val[r] = (i < NPIX);
            pki[r] = val[r] ? (((unsigned long long)ukey[i] << 10) | (unsigned)i) : 0ull;
        }
        const uint4* k4 = (const uint4*)ukey;
        for (int c = 0; c < NPIX / 4; ++c) {
            uint4 kv = k4[c];
            unsigned q = 4u * c;
            unsigned long long p0 = ((unsigned long long)kv.x << 10) | q;
            unsigned long long p1 = ((unsigned long long)kv.y << 10) | (q + 1);
            unsigned long long p2 = ((unsigned long long)kv.z << 10) | (q + 2);
            unsigned long long p3 = ((unsigned long long)kv.w << 10) | (q + 3);
            #pragma unroll
            for (int r = 0; r < 4; ++r) {
                rank[r] += (int)(p0 < pki[r]) + (int)(p1 < pki[r])
                         + (int)(p2 < pki[r]) + (int)(p3 < pki[r]);
            }
        }
        #pragma unroll
        for (int r = 0; r < 4; ++r) {
            if (val[r]) {
                int i = tid + 256 * r;
                posA[i] = rank[r];
                ordA[rank[r]] = i;
            }
        }
    }
    __syncthreads();
    for (int s = tid; s < NPIX; s += 256) comp[s] = (posA[s] << 10) | s;
    // (comp init needs no barrier before P2: P2 reads only posA)

    int k;
    if (dir == 0) k = uf_basin_run<4>(posA, ordA, bas, comp, recs, pairsI,
                                      mergeLDS, shInts, wtot4);
    else          k = uf_basin_run<8>(posA, ordA, bas, comp, recs, pairsI,
                                      mergeLDS, shInts, wtot4);

    // convert packed pairs to (b, d) float values (dir 1 stores swapped)
    for (int s = tid; s < k; s += 256) {
        int p = pairsI[s];
        float fb = fv[p & 1023], fd = fv[p >> 10];
        pairs[s] = dir ? make_float2(fd, fb) : make_float2(fb, fd);
    }
    __syncthreads();

    // ---- fused landscape: top-3 tents over the k real pairs ----
    if (tid < 32) {
        int t = tid;
        float start = (feat == 0) ? 0.f : 1.f;
        float end   = (feat == 0) ? 7.f : 8.f;
        float tv = start + (end - start) * ((float)t / 31.f);
        float v0 = 0.f, v1 = 0.f, v2 = 0.f;
        for (int p = 0; p < k; ++p) {
            float2 bd = pairs[p];
            float tent = fmaxf(fminf(tv - bd.x, bd.y - tv), 0.f);
            if (tent > v0)      { v2 = v1; v1 = v0; v0 = tent; }
            else if (tent > v1) { v2 = v1; v1 = tent; }
            else if (tent > v2) { v2 = tent; }
        }
        if (feat == 0) {
            float* lam = LAM1 + m * 128 + dir * 64;
            lam[0 * 32 + t] = v0;
            lam[1 * 32 + t] = v1;
        } else {
            float* lam = LAM2 + m * 192 + dir * 96;
            lam[0 * 32 + t] = v0;
            lam[1 * 32 + t] = v1;
            lam[2 * 32 + t] = v2;
        }
    }
}

// ---------------------------------------------------------------------------
// Kernel 4: MLP head. One block (64 threads) per image.
// ---------------------------------------------------------------------------
__global__ void mlp_kernel(const float* __restrict__ LAM1, const float* __restrict__ LAM2,
                           const float* __restrict__ w1, const float* __restrict__ b1,
                           const float* __restrict__ w2, const float* __restrict__ b2,
                           const float* __restrict__ wf, const float* __restrict__ bf,
                           float* __restrict__ out) {
    __shared__ float xc[64];
    int m = blockIdx.x;
    int n = threadIdx.x;
    if (n < 32) {
        float acc = b1[n];
        const float* l = LAM1 + m * 128;
        for (int c = 0; c < 128; ++c) acc += w1[n * 128 + c] * l[c];
        xc[n] = fmaxf(acc, 0.f);
    } else {
        int n2 = n - 32;
        float acc = b2[n2];
        const float* l = LAM2 + m * 192;
        for (int c = 0; c < 192; ++c) acc += w2[n2 * 192 + c] * l[c];
        xc[n] = fmaxf(acc, 0.f);
    }
    __syncthreads();
    if (n < 10) {
        float acc = bf[n];
        for (int c = 0; c < 64; ++c) acc += wf[n * 64 + c] * xc[c];
        out[m * 10 + n] = acc;
    }
}

extern "C" void kernel_launch(void* const* d_in, const int* in_sizes, int n_in,
                              void* d_out, int out_size, void* d_ws, size_t ws_size,
                              hipStream_t stream) {
    const float* x  = (const float*)d_in[0];
    const float* w1 = (const float*)d_in[1];
    const float* b1 = (const float*)d_in[2];
    const float* w2 = (const float*)d_in[3];
    const float* b2 = (const float*)d_in[4];
    const float* wf = (const float*)d_in[5];
    const float* bf = (const float*)d_in[6];
    float* out = (float*)d_out;

    char* ws = (char*)d_ws;
    size_t off = 0;
    unsigned short* SORT = (unsigned short*)(ws + off); off += (size_t)NPIX * NPIX * 2;
    unsigned short* D2S  = (unsigned short*)(ws + off); off += (size_t)NPIX * NPIX * 2;
    float* SUMS = (float*)(ws + off); off += 256;
    float* F    = (float*)(ws + off); off += (size_t)2 * NIMG * NPIX * 4;
    float* LAM1 = (float*)(ws + off); off += (size_t)NIMG * 128 * 4;
    float* LAM2 = (float*)(ws + off); off += (size_t)NIMG * 192 * 4;

    consts_sums_kernel<<<NPIX + NIMG, 256, 0, stream>>>(SORT, D2S, x, SUMS);
    dtm_kernel<<<(NIMG * NPIX) / 4, 256, 0, stream>>>(x, SORT, D2S, SUMS, F);
    uf_land_kernel<<<256, 256, 0, stream>>>(F, LAM1, LAM2);
    mlp_kernel<<<NIMG, 64, 0, stream>>>(LAM1, LAM2, w1, b1, w2, b2, wf, bf, out);
}